// Round 2
// baseline (1156.131 us; speedup 1.0000x reference)
//
#include <hip/hip_runtime.h>
#include <hip/hip_bf16.h>

#define B_GRAPH 128
#define ETOT    (128*4096)   // 524288 edges (static)
#define N0G     (128*512)    // 65536 nodes at level 0
#define HF      128

// ---------------- init ----------------
__global__ __launch_bounds__(256) void k_fill1(float* w, int n){
    int i = blockIdx.x*256 + threadIdx.x;
    if (i < n) w[i] = 1.0f;
}

// ---------------- CSR build ----------------
__global__ __launch_bounds__(256) void k_hist(const int* __restrict__ dst, const float* __restrict__ w,
                                              int* __restrict__ cnt){
    int e = blockIdx.x*256 + threadIdx.x;
    if (e < ETOT && w[e] > 0.5f) atomicAdd(&cnt[dst[e]], 1);
}
__global__ __launch_bounds__(1024) void k_scan(const int* __restrict__ cnt, int* __restrict__ rowptr, int Nn){
    __shared__ int part[1024];
    int t = threadIdx.x;
    int C = (Nn + 1023) >> 10;
    int lo = t*C; if (lo > Nn) lo = Nn;
    int hi = lo + C; if (hi > Nn) hi = Nn;
    int s = 0;
    for (int i = lo; i < hi; ++i) s += cnt[i];
    part[t] = s;
    __syncthreads();
    for (int off = 1; off < 1024; off <<= 1){
        int add = (t >= off) ? part[t-off] : 0;
        __syncthreads();
        part[t] += add;
        __syncthreads();
    }
    int run = part[t] - s;   // exclusive prefix of this chunk
    for (int i = lo; i < hi; ++i){ rowptr[i] = run; run += cnt[i]; }
    if (t == 1023) rowptr[Nn] = part[1023];
}
__global__ __launch_bounds__(256) void k_dinv(const int* __restrict__ cnt, const int* __restrict__ rowptr,
                                              float* __restrict__ dinv, int* __restrict__ cursor, int Nn){
    int v = blockIdx.x*256 + threadIdx.x;
    if (v < Nn){
        dinv[v] = rsqrtf((float)cnt[v] + 1.0f);
        cursor[v] = rowptr[v];
    }
}
__global__ __launch_bounds__(256) void k_scatter(const int* __restrict__ src, const int* __restrict__ dst,
                                                 const float* __restrict__ w,
                                                 int* __restrict__ cursor, int* __restrict__ csr_s){
    int e = blockIdx.x*256 + threadIdx.x;
    if (e < ETOT && w[e] > 0.5f){
        int d = dst[e];
        int p = atomicAdd(&cursor[d], 1);
        csr_s[p] = src[e];
    }
}

// ---------------- GEMM: C[N,128] = A[N,128] @ W[128,128] (all fp32) ----------------
__global__ __launch_bounds__(256) void k_gemm(const float* __restrict__ A, const float* __restrict__ Wg,
                                              float* __restrict__ C){
    __shared__ float Ws[HF*HF];
    for (int i = threadIdx.x; i < HF*HF; i += 256) Ws[i] = Wg[i];
    __syncthreads();
    int m0 = blockIdx.x * 64;
    int tx = threadIdx.x & 15, ty = threadIdx.x >> 4;
    int r0 = m0 + ty*4, c0 = tx*8;
    float acc[4][8];
    #pragma unroll
    for (int j=0;j<4;++j)
        #pragma unroll
        for (int l=0;l<8;++l) acc[j][l] = 0.f;
    for (int k4 = 0; k4 < 32; ++k4){
        float4 av[4];
        #pragma unroll
        for (int j=0;j<4;++j)
            av[j] = *(const float4*)(A + (size_t)(r0+j)*HF + k4*4);
        #pragma unroll
        for (int kk=0; kk<4; ++kk){
            const float* wr = Ws + (k4*4+kk)*HF + c0;
            float bv[8];
            #pragma unroll
            for (int l=0;l<8;++l) bv[l] = wr[l];
            #pragma unroll
            for (int j=0;j<4;++j){
                float a = reinterpret_cast<const float*>(&av[j])[kk];
                #pragma unroll
                for (int l=0;l<8;++l) acc[j][l] += a*bv[l];
            }
        }
    }
    #pragma unroll
    for (int j=0;j<4;++j){
        float4 o0 = make_float4(acc[j][0],acc[j][1],acc[j][2],acc[j][3]);
        float4 o1 = make_float4(acc[j][4],acc[j][5],acc[j][6],acc[j][7]);
        *(float4*)(C + (size_t)(r0+j)*HF + c0)     = o0;
        *(float4*)(C + (size_t)(r0+j)*HF + c0 + 4) = o1;
    }
}

// ---------------- prop: X[v] = Y[v]*dv*dv + dv * sum_e dinv[s]*Y[s] + convb ----------------
__global__ __launch_bounds__(256) void k_prop(const float* __restrict__ Y, const float* __restrict__ cb,
                                              const int* __restrict__ rowptr, const int* __restrict__ cs,
                                              const float* __restrict__ dinv,
                                              float* __restrict__ X, int Nn){
    int gid = blockIdx.x*256 + threadIdx.x;
    int v = gid >> 5, f4 = gid & 31;
    if (v >= Nn) return;
    float dv = dinv[v];
    float4 y = *(const float4*)(Y + (size_t)v*HF + f4*4);
    float4 acc = make_float4(0.f, 0.f, 0.f, 0.f);
    int e1 = rowptr[v+1];
    for (int j = rowptr[v]; j < e1; ++j){
        int s = cs[j] & (Nn - 1);       // Nn is a power of two; mask = OOB insurance
        float en = dinv[s];
        float4 h = *(const float4*)(Y + (size_t)s*HF + f4*4);
        acc.x += en*h.x; acc.y += en*h.y; acc.z += en*h.z; acc.w += en*h.w;
    }
    int f = f4*4;
    acc.x = y.x*dv*dv + dv*acc.x + cb[f];
    acc.y = y.y*dv*dv + dv*acc.y + cb[f+1];
    acc.z = y.z*dv*dv + dv*acc.z + cb[f+2];
    acc.w = y.w*dv*dv + dv*acc.w + cb[f+3];
    *(float4*)(X + (size_t)v*HF + f) = acc;
}

// ---------------- BN stats (sum, sumsq per column) ----------------
__global__ __launch_bounds__(256) void k_bnstats(const float* __restrict__ X, float* __restrict__ stats){
    int c = threadIdx.x & 127, h = threadIdx.x >> 7;
    int r0 = blockIdx.x * 256;
    float s = 0.f, s2 = 0.f;
    for (int r = r0 + h; r < r0 + 256; r += 2){
        float x = X[(size_t)r*HF + c];
        s += x; s2 += x*x;
    }
    __shared__ float l1[256], l2[256];
    l1[threadIdx.x] = s; l2[threadIdx.x] = s2;
    __syncthreads();
    if (threadIdx.x < 128){
        atomicAdd(&stats[c],     l1[threadIdx.x] + l1[threadIdx.x+128]);
        atomicAdd(&stats[128+c], l2[threadIdx.x] + l2[threadIdx.x+128]);
    }
}

// ---------------- BN apply + ReLU + s0 = h @ attW ----------------
__global__ __launch_bounds__(256) void k_bn_s0(float* __restrict__ X, const float* __restrict__ gw,
                                               const float* __restrict__ gb, const float* __restrict__ aw,
                                               const float* __restrict__ stats, float* __restrict__ p0,
                                               float invN){
    int f = threadIdx.x & 127, rl = threadIdx.x >> 7;
    int r = blockIdx.x*2 + rl;
    float mean = stats[f]*invN;
    float var  = stats[128+f]*invN - mean*mean;
    float iv   = rsqrtf(var + 1e-5f);
    float x = X[(size_t)r*HF + f];
    float val = (x - mean)*iv*gw[f] + gb[f];
    val = fmaxf(val, 0.f);
    X[(size_t)r*HF + f] = val;
    __shared__ float red[256];
    red[threadIdx.x] = val * aw[f];
    __syncthreads();
    for (int off = 64; off; off >>= 1){
        if (f < off) red[threadIdx.x] += red[threadIdx.x + off];
        __syncthreads();
    }
    if (f == 0) p0[r] = red[rl << 7];
}

// ---------------- fused Jacobi step: p_new = ca*tin + cc*prev ; out_t = pvec(p_new) ----------------
__global__ __launch_bounds__(256) void k_pvec(const float* __restrict__ tin, const float* __restrict__ prev,
                                              const int* __restrict__ rowptr, const int* __restrict__ cs,
                                              const float* __restrict__ dinv,
                                              float* __restrict__ outt, float* __restrict__ outp,
                                              float ca, float cc, int Nn){
    int v = blockIdx.x*256 + threadIdx.x;
    if (v >= Nn) return;
    float pv = ca*tin[v] + cc*prev[v];
    outp[v] = pv;
    float dv = dinv[v];
    float acc = 0.f;
    int e1 = rowptr[v+1];
    for (int j = rowptr[v]; j < e1; ++j){
        int s = cs[j] & (Nn - 1);
        float ps = ca*tin[s] + cc*prev[s];
        acc += dinv[s]*ps;
    }
    outt[v] = pv*dv*dv + dv*acc;
}
__global__ __launch_bounds__(256) void k_score(const float* __restrict__ tin, const float* __restrict__ p2,
                                               const float* __restrict__ p1, const float* __restrict__ p0,
                                               const float* __restrict__ th, float* __restrict__ score,
                                               float ca, float cc, int Nn){
    int v = blockIdx.x*256 + threadIdx.x;
    if (v >= Nn) return;
    float p3 = ca*tin[v] + cc*p1[v];
    score[v] = th[0]*p0[v] + th[1]*p1[v] + th[2]*p2[v] + th[3]*p3;
}

// ---------------- per-graph top-k (bitonic, desc score, ties -> lower idx) ----------------
__global__ __launch_bounds__(256) void k_topk(const float* __restrict__ score, float* __restrict__ ts,
                                              int* __restrict__ newid, int* __restrict__ selmap,
                                              int n, int k){
    __shared__ float ss[512];
    __shared__ int   si[512];
    int g = blockIdx.x, t = threadIdx.x;
    for (int i = t; i < n; i += 256){ ss[i] = score[g*n + i]; si[i] = i; }
    __syncthreads();
    for (int size = 2; size <= n; size <<= 1){
        for (int stride = size >> 1; stride > 0; stride >>= 1){
            for (int i = t; i < n; i += 256){
                int j = i ^ stride;
                if (j > i){
                    bool asc = ((i & size) == 0);
                    float s1 = ss[i], s2 = ss[j];
                    int   i1 = si[i], i2 = si[j];
                    // key = (-score, idx); keyGreater:
                    bool gt = (s1 < s2) || (s1 == s2 && i1 > i2);
                    if (gt == asc){ ss[i] = s2; ss[j] = s1; si[i] = i2; si[j] = i1; }
                }
            }
            __syncthreads();
        }
    }
    for (int r = t; r < k; r += 256){
        int old = g*n + si[r];
        int nw  = g*k + r;
        newid[old] = nw;
        selmap[nw] = old;
        ts[nw] = tanhf(ss[r]);
    }
}

// ---------------- gather pooled nodes ----------------
__global__ __launch_bounds__(256) void k_gather(const float* __restrict__ X, const int* __restrict__ selmap,
                                                const float* __restrict__ ts, float* __restrict__ Y, int Nk){
    int gid = blockIdx.x*256 + threadIdx.x;
    int v = gid >> 5, f4 = gid & 31;
    if (v >= Nk) return;
    int o = selmap[v];
    float t = ts[v];
    float4 x = *(const float4*)(X + (size_t)o*HF + f4*4);
    x.x *= t; x.y *= t; x.z *= t; x.w *= t;
    *(float4*)(Y + (size_t)v*HF + f4*4) = x;
}

// ---------------- readout: gacc[g] += [max_j h, mean_j h] ----------------
__global__ __launch_bounds__(256) void k_readout(const float* __restrict__ Y, float* __restrict__ gacc, int k){
    int f = threadIdx.x & 127, h = threadIdx.x >> 7, g = blockIdx.x;
    float mx = -3.4e38f, sm = 0.f;
    for (int j = h; j < k; j += 2){
        float x = Y[((size_t)g*k + j)*HF + f];
        mx = fmaxf(mx, x); sm += x;
    }
    __shared__ float l1[256], l2[256];
    l1[threadIdx.x] = mx; l2[threadIdx.x] = sm;
    __syncthreads();
    if (threadIdx.x < 128){
        mx = fmaxf(l1[f], l1[f+128]);
        sm = l2[f] + l2[f+128];
        gacc[g*256 + f]       += mx;
        gacc[g*256 + 128 + f] += sm / (float)k;
    }
}

// ---------------- edge remap ----------------
__global__ __launch_bounds__(256) void k_remap(int* __restrict__ src, int* __restrict__ dst,
                                               float* __restrict__ w, const int* __restrict__ newid){
    int e = blockIdx.x*256 + threadIdx.x;
    if (e >= ETOT) return;
    if (w[e] > 0.5f){
        int ns = newid[src[e]], nd = newid[dst[e]];
        if (ns >= 0 && nd >= 0){ src[e] = ns; dst[e] = nd; }
        else { src[e] = 0; dst[e] = 0; w[e] = 0.f; }
    } else { src[e] = 0; dst[e] = 0; }
}

// ---------------- head ----------------
__global__ __launch_bounds__(256) void k_lin(const float* __restrict__ in, const float* __restrict__ W,
                                             const float* __restrict__ bias, float* __restrict__ out,
                                             int K, int Ncol, float scale){
    int gid = blockIdx.x*256 + threadIdx.x;
    int r = gid / Ncol, c = gid - r*Ncol;
    float s = 0.f;
    for (int kk = 0; kk < K; ++kk) s += in[r*K + kk] * W[kk*Ncol + c];
    out[r*Ncol + c] = s*scale + bias[c];
}
__global__ void k_bn_head(float* __restrict__ t, const float* __restrict__ gw, const float* __restrict__ gb,
                          int Ncol){
    int c = threadIdx.x;
    float s = 0.f, s2 = 0.f;
    for (int r = 0; r < 128; ++r){ float x = t[r*Ncol + c]; s += x; s2 += x*x; }
    float mean = s * (1.f/128.f);
    float var  = s2 * (1.f/128.f) - mean*mean;
    float iv   = rsqrtf(var + 1e-5f);
    float ga = gw[c], be = gb[c];
    for (int r = 0; r < 128; ++r){
        float x = t[r*Ncol + c];
        t[r*Ncol + c] = fmaxf((x - mean)*iv*ga + be, 0.f);
    }
}
__global__ void k_head_out(const float* __restrict__ t2, const float* __restrict__ W,
                           const float* __restrict__ bias, float* __restrict__ out){
    int r = threadIdx.x;  // 128 rows
    float lg[10];
    float m = -3.4e38f;
    for (int j = 0; j < 10; ++j){
        float s = bias[j];
        for (int kk = 0; kk < 64; ++kk) s += t2[r*64 + kk] * W[kk*10 + j];
        lg[j] = s; m = fmaxf(m, s);
    }
    float se = 0.f;
    for (int j = 0; j < 10; ++j) se += expf(lg[j] - m);
    float l = logf(se) + m;
    for (int j = 0; j < 10; ++j) out[r*10 + j] = lg[j] - l;
}

extern "C" void kernel_launch(void* const* d_in, const int* in_sizes, int n_in,
                              void* d_out, int out_size, void* d_ws, size_t ws_size,
                              hipStream_t stream){
    const float* x     = (const float*)d_in[0];
    const float* convW = (const float*)d_in[1];
    const float* convb = (const float*)d_in[2];
    const float* bnW   = (const float*)d_in[3];
    const float* bnB   = (const float*)d_in[4];
    const float* bn7W  = (const float*)d_in[5];
    const float* bn7B  = (const float*)d_in[6];
    const float* attW  = (const float*)d_in[7];
    const float* theta = (const float*)d_in[8];
    const float* lin1W = (const float*)d_in[9];
    const float* lin1b = (const float*)d_in[10];
    const float* lin2W = (const float*)d_in[11];
    const float* lin2b = (const float*)d_in[12];
    const float* lin3W = (const float*)d_in[13];
    const float* lin3b = (const float*)d_in[14];

    char* base = (char*)d_ws;
    size_t off = 0;
    auto take = [&](size_t bytes) -> void* {
        void* p = base + off;
        off = (off + bytes + 255) & ~(size_t)255;
        return p;
    };
    float* bufA  = (float*)take((size_t)N0G*HF*4);
    float* bufB  = (float*)take((size_t)N0G*HF*4);
    float* w     = (float*)take((size_t)ETOT*4);
    int*   srcw  = (int*)  take((size_t)ETOT*4);
    int*   dstw  = (int*)  take((size_t)ETOT*4);
    int*   cnt   = (int*)  take((size_t)N0G*4);
    int*   rowp  = (int*)  take((size_t)(N0G+1)*4);
    int*   curs  = (int*)  take((size_t)N0G*4);
    float* dinv  = (float*)take((size_t)N0G*4);
    int*   csr_s = (int*)  take((size_t)ETOT*4);
    float* p0v   = (float*)take((size_t)N0G*4);
    float* p1v   = (float*)take((size_t)N0G*4);
    float* p2v   = (float*)take((size_t)N0G*4);
    float* tAv   = (float*)take((size_t)N0G*4);
    float* tBv   = (float*)take((size_t)N0G*4);
    float* scv   = (float*)take((size_t)N0G*4);
    float* tsv   = (float*)take((size_t)(N0G/2)*4);
    int*   newid = (int*)  take((size_t)N0G*4);
    int*   selmap= (int*)  take((size_t)(N0G/2)*4);
    float* stats = (float*)take(256*4);
    float* gacc  = (float*)take((size_t)B_GRAPH*256*4);
    float* t1    = (float*)take((size_t)B_GRAPH*128*4);
    float* t2    = (float*)take((size_t)B_GRAPH*64*4);

    // Jacobi coefficients (A=B=1 -> c2 term is 0)
    auto coef = [](int kk, float& ca, float& cc){
        double a = 1.0, b = 1.0;
        double c0 = 2.0*kk*(kk+a+b)*(2.0*kk+a+b-2.0);
        double c1 = (2.0*kk+a+b-1.0)*(2.0*kk+a+b)*(2.0*kk+a+b-2.0);
        double c3 = 2.0*(kk+a-1.0)*(kk+b-1.0)*(2.0*kk+a+b);
        ca = (float)(c1/c0); cc = (float)(-c3/c0);
    };
    float ca2, cc2, ca3, cc3;
    coef(2, ca2, cc2);
    coef(3, ca3, cc3);

    hipMemcpyAsync(srcw, d_in[15], (size_t)ETOT*4, hipMemcpyDeviceToDevice, stream);
    hipMemcpyAsync(dstw, d_in[16], (size_t)ETOT*4, hipMemcpyDeviceToDevice, stream);
    k_fill1<<<ETOT/256, 256, 0, stream>>>(w, ETOT);
    hipMemsetAsync(gacc, 0, (size_t)B_GRAPH*256*4, stream);

    for (int i = 0; i < 5; ++i){
        int n = 512 >> i, k = n >> 1;
        int Nn = B_GRAPH*n, Nk = B_GRAPH*k;
        float* hin = (i & 1) ? bufB : bufA;
        float* tmp = (i & 1) ? bufA : bufB;
        const float* gemmA = (i == 0) ? x : hin;   // level 0 reads x directly

        hipMemsetAsync(cnt, 0, (size_t)Nn*4, stream);
        k_hist<<<ETOT/256, 256, 0, stream>>>(dstw, w, cnt);
        k_scan<<<1, 1024, 0, stream>>>(cnt, rowp, Nn);
        k_dinv<<<Nn/256, 256, 0, stream>>>(cnt, rowp, dinv, curs, Nn);
        k_scatter<<<ETOT/256, 256, 0, stream>>>(srcw, dstw, w, curs, csr_s);

        k_gemm<<<Nn/64, 256, 0, stream>>>(gemmA, convW + (size_t)i*HF*HF, tmp);
        k_prop<<<(Nn*32)/256, 256, 0, stream>>>(tmp, convb + i*HF, rowp, csr_s, dinv, hin, Nn);

        hipMemsetAsync(stats, 0, 256*4, stream);
        k_bnstats<<<Nn/256, 256, 0, stream>>>(hin, stats);
        k_bn_s0<<<Nn/2, 256, 0, stream>>>(hin, bnW + i*HF, bnB + i*HF, attW + i*HF, stats, p0v, 1.0f/(float)Nn);

        // Jacobi: t0=pvec(p0); p1=2*t0, t1=pvec(p1); p2=ca2*t1+cc2*p0, t2=pvec(p2); p3=ca3*t2+cc3*p1
        k_pvec<<<Nn/256, 256, 0, stream>>>(p0v, p0v, rowp, csr_s, dinv, tAv, scv, 1.0f, 0.0f, Nn);
        k_pvec<<<Nn/256, 256, 0, stream>>>(tAv, p0v, rowp, csr_s, dinv, tBv, p1v, 2.0f, 0.0f, Nn);
        k_pvec<<<Nn/256, 256, 0, stream>>>(tBv, p0v, rowp, csr_s, dinv, tAv, p2v, ca2, cc2, Nn);
        k_score<<<Nn/256, 256, 0, stream>>>(tAv, p2v, p1v, p0v, theta + i*4, scv, ca3, cc3, Nn);

        hipMemsetAsync(newid, 0xFF, (size_t)Nn*4, stream);   // -1
        k_topk<<<B_GRAPH, 256, 0, stream>>>(scv, tsv, newid, selmap, n, k);
        k_gather<<<(Nk*32)/256, 256, 0, stream>>>(hin, selmap, tsv, tmp, Nk);
        k_readout<<<B_GRAPH, 256, 0, stream>>>(tmp, gacc, k);
        k_remap<<<ETOT/256, 256, 0, stream>>>(srcw, dstw, w, newid);
    }

    k_lin<<<(B_GRAPH*128)/256, 256, 0, stream>>>(gacc, lin1W, lin1b, t1, 256, 128, 0.2f);
    k_bn_head<<<1, 128, 0, stream>>>(t1, bnW + 5*HF, bnB + 5*HF, 128);
    k_lin<<<(B_GRAPH*64)/256, 256, 0, stream>>>(t1, lin2W, lin2b, t2, 128, 64, 1.0f);
    k_bn_head<<<1, 64, 0, stream>>>(t2, bn7W, bn7B, 64);
    k_head_out<<<1, 128, 0, stream>>>(t2, lin3W, lin3b, (float*)d_out);
}

// Round 3
// 990.663 us; speedup vs baseline: 1.1670x; 1.1670x over previous
//
#include <hip/hip_runtime.h>
#include <hip/hip_bf16.h>

#define B_GRAPH 128
#define ETOT    (128*4096)   // 524288 edges (static)
#define N0G     (128*512)    // 65536 nodes at level 0
#define HF      128

// ---------------- init ----------------
__global__ __launch_bounds__(256) void k_fill1(float* w, int n){
    int i = blockIdx.x*256 + threadIdx.x;
    if (i < n) w[i] = 1.0f;
}

// ---------------- CSR build ----------------
__global__ __launch_bounds__(256) void k_hist(const int* __restrict__ dst, const float* __restrict__ w,
                                              int* __restrict__ cnt){
    int e = blockIdx.x*256 + threadIdx.x;
    if (e < ETOT && w[e] > 0.5f) atomicAdd(&cnt[dst[e]], 1);
}

// two-level scan: k_part (per-block sums) -> k_mid (scan of partials) -> k_final (block scan + dinv/cursor)
__global__ __launch_bounds__(256) void k_part(const int* __restrict__ cnt, int* __restrict__ psum){
    __shared__ int red[256];
    int t = threadIdx.x;
    red[t] = cnt[blockIdx.x*256 + t];
    __syncthreads();
    for (int off = 128; off; off >>= 1){
        if (t < off) red[t] += red[t + off];
        __syncthreads();
    }
    if (t == 0) psum[blockIdx.x] = red[0];
}
__global__ __launch_bounds__(256) void k_mid(const int* __restrict__ psum, int* __restrict__ boff,
                                             int* __restrict__ rowptr, int nb, int Nn){
    __shared__ int s[256];
    int t = threadIdx.x;
    int v = (t < nb) ? psum[t] : 0;
    s[t] = v;
    __syncthreads();
    for (int off = 1; off < 256; off <<= 1){
        int a = (t >= off) ? s[t-off] : 0;
        __syncthreads();
        s[t] += a;
        __syncthreads();
    }
    if (t < nb) boff[t] = s[t] - v;       // exclusive block offset
    if (t == nb-1) rowptr[Nn] = s[t];     // total
}
__global__ __launch_bounds__(256) void k_final(const int* __restrict__ cnt, const int* __restrict__ boff,
                                               int* __restrict__ rowptr, float* __restrict__ dinv,
                                               int* __restrict__ cursor){
    __shared__ int s[256];
    int t = threadIdx.x, i = blockIdx.x*256 + t;
    int c = cnt[i];
    s[t] = c;
    __syncthreads();
    for (int off = 1; off < 256; off <<= 1){
        int a = (t >= off) ? s[t-off] : 0;
        __syncthreads();
        s[t] += a;
        __syncthreads();
    }
    int rp = boff[blockIdx.x] + s[t] - c;  // exclusive prefix
    rowptr[i] = rp;
    cursor[i] = rp;
    dinv[i]   = rsqrtf((float)c + 1.0f);
}

__global__ __launch_bounds__(256) void k_scatter(const int* __restrict__ src, const int* __restrict__ dst,
                                                 const float* __restrict__ w,
                                                 int* __restrict__ cursor, int* __restrict__ csr_s){
    int e = blockIdx.x*256 + threadIdx.x;
    if (e < ETOT && w[e] > 0.5f){
        int d = dst[e];
        int p = atomicAdd(&cursor[d], 1);
        csr_s[p] = src[e];
    }
}

// ---------------- GEMM: C[N,128] = A[N,128] @ W[128,128] (all fp32) ----------------
__global__ __launch_bounds__(256) void k_gemm(const float* __restrict__ A, const float* __restrict__ Wg,
                                              float* __restrict__ C){
    __shared__ float Ws[HF*HF];
    for (int i = threadIdx.x; i < HF*HF; i += 256) Ws[i] = Wg[i];
    __syncthreads();
    int m0 = blockIdx.x * 64;
    int tx = threadIdx.x & 15, ty = threadIdx.x >> 4;
    int r0 = m0 + ty*4, c0 = tx*8;
    float acc[4][8];
    #pragma unroll
    for (int j=0;j<4;++j)
        #pragma unroll
        for (int l=0;l<8;++l) acc[j][l] = 0.f;
    for (int k4 = 0; k4 < 32; ++k4){
        float4 av[4];
        #pragma unroll
        for (int j=0;j<4;++j)
            av[j] = *(const float4*)(A + (size_t)(r0+j)*HF + k4*4);
        #pragma unroll
        for (int kk=0; kk<4; ++kk){
            const float* wr = Ws + (k4*4+kk)*HF + c0;
            float bv[8];
            #pragma unroll
            for (int l=0;l<8;++l) bv[l] = wr[l];
            #pragma unroll
            for (int j=0;j<4;++j){
                float a = reinterpret_cast<const float*>(&av[j])[kk];
                #pragma unroll
                for (int l=0;l<8;++l) acc[j][l] += a*bv[l];
            }
        }
    }
    #pragma unroll
    for (int j=0;j<4;++j){
        float4 o0 = make_float4(acc[j][0],acc[j][1],acc[j][2],acc[j][3]);
        float4 o1 = make_float4(acc[j][4],acc[j][5],acc[j][6],acc[j][7]);
        *(float4*)(C + (size_t)(r0+j)*HF + c0)     = o0;
        *(float4*)(C + (size_t)(r0+j)*HF + c0 + 4) = o1;
    }
}

// ---------------- prop: X[v] = Y[v]*dv*dv + dv * sum_e dinv[s]*Y[s] + convb ----------------
__global__ __launch_bounds__(256) void k_prop(const float* __restrict__ Y, const float* __restrict__ cb,
                                              const int* __restrict__ rowptr, const int* __restrict__ cs,
                                              const float* __restrict__ dinv,
                                              float* __restrict__ X, int Nn){
    int gid = blockIdx.x*256 + threadIdx.x;
    int v = gid >> 5, f4 = gid & 31;
    if (v >= Nn) return;
    float dv = dinv[v];
    float4 y = *(const float4*)(Y + (size_t)v*HF + f4*4);
    float4 acc = make_float4(0.f, 0.f, 0.f, 0.f);
    int e1 = rowptr[v+1];
    for (int j = rowptr[v]; j < e1; ++j){
        int s = cs[j] & (Nn - 1);       // Nn is a power of two; mask = OOB insurance
        float en = dinv[s];
        float4 h = *(const float4*)(Y + (size_t)s*HF + f4*4);
        acc.x += en*h.x; acc.y += en*h.y; acc.z += en*h.z; acc.w += en*h.w;
    }
    int f = f4*4;
    acc.x = y.x*dv*dv + dv*acc.x + cb[f];
    acc.y = y.y*dv*dv + dv*acc.y + cb[f+1];
    acc.z = y.z*dv*dv + dv*acc.z + cb[f+2];
    acc.w = y.w*dv*dv + dv*acc.w + cb[f+3];
    *(float4*)(X + (size_t)v*HF + f) = acc;
}

// ---------------- BN stats (sum, sumsq per column) ----------------
__global__ __launch_bounds__(256) void k_bnstats(const float* __restrict__ X, float* __restrict__ stats){
    int c = threadIdx.x & 127, h = threadIdx.x >> 7;
    int r0 = blockIdx.x * 256;
    float s = 0.f, s2 = 0.f;
    for (int r = r0 + h; r < r0 + 256; r += 2){
        float x = X[(size_t)r*HF + c];
        s += x; s2 += x*x;
    }
    __shared__ float l1[256], l2[256];
    l1[threadIdx.x] = s; l2[threadIdx.x] = s2;
    __syncthreads();
    if (threadIdx.x < 128){
        atomicAdd(&stats[c],     l1[threadIdx.x] + l1[threadIdx.x+128]);
        atomicAdd(&stats[128+c], l2[threadIdx.x] + l2[threadIdx.x+128]);
    }
}

// ---------------- BN apply + ReLU + s0 = h @ attW ----------------
__global__ __launch_bounds__(256) void k_bn_s0(float* __restrict__ X, const float* __restrict__ gw,
                                               const float* __restrict__ gb, const float* __restrict__ aw,
                                               const float* __restrict__ stats, float* __restrict__ p0,
                                               float invN){
    int f = threadIdx.x & 127, rl = threadIdx.x >> 7;
    int r = blockIdx.x*2 + rl;
    float mean = stats[f]*invN;
    float var  = stats[128+f]*invN - mean*mean;
    float iv   = rsqrtf(var + 1e-5f);
    float x = X[(size_t)r*HF + f];
    float val = (x - mean)*iv*gw[f] + gb[f];
    val = fmaxf(val, 0.f);
    X[(size_t)r*HF + f] = val;
    __shared__ float red[256];
    red[threadIdx.x] = val * aw[f];
    __syncthreads();
    for (int off = 64; off; off >>= 1){
        if (f < off) red[threadIdx.x] += red[threadIdx.x + off];
        __syncthreads();
    }
    if (f == 0) p0[r] = red[rl << 7];
}

// ---------------- fused Jacobi step: p_new = ca*tin + cc*prev ; out_t = pvec(p_new) ----------------
__global__ __launch_bounds__(256) void k_pvec(const float* __restrict__ tin, const float* __restrict__ prev,
                                              const int* __restrict__ rowptr, const int* __restrict__ cs,
                                              const float* __restrict__ dinv,
                                              float* __restrict__ outt, float* __restrict__ outp,
                                              float ca, float cc, int Nn){
    int v = blockIdx.x*256 + threadIdx.x;
    if (v >= Nn) return;
    float pv = ca*tin[v] + cc*prev[v];
    outp[v] = pv;
    float dv = dinv[v];
    float acc = 0.f;
    int e1 = rowptr[v+1];
    for (int j = rowptr[v]; j < e1; ++j){
        int s = cs[j] & (Nn - 1);
        float ps = ca*tin[s] + cc*prev[s];
        acc += dinv[s]*ps;
    }
    outt[v] = pv*dv*dv + dv*acc;
}
// last Jacobi step + theta combine fused (p3 needs only thread-local t2)
__global__ __launch_bounds__(256) void k_pvec_score(const float* __restrict__ tin,  // t1
                                                    const float* __restrict__ prev, // p0
                                                    const float* __restrict__ p1,
                                                    const int* __restrict__ rowptr, const int* __restrict__ cs,
                                                    const float* __restrict__ dinv, const float* __restrict__ th,
                                                    float* __restrict__ score,
                                                    float ca2, float cc2, float ca3, float cc3, int Nn){
    int v = blockIdx.x*256 + threadIdx.x;
    if (v >= Nn) return;
    float p2 = ca2*tin[v] + cc2*prev[v];
    float dv = dinv[v];
    float acc = 0.f;
    int e1 = rowptr[v+1];
    for (int j = rowptr[v]; j < e1; ++j){
        int s = cs[j] & (Nn - 1);
        acc += dinv[s]*(ca2*tin[s] + cc2*prev[s]);
    }
    float t2 = p2*dv*dv + dv*acc;
    float p3 = ca3*t2 + cc3*p1[v];
    score[v] = th[0]*prev[v] + th[1]*p1[v] + th[2]*p2 + th[3]*p3;
}

// ---------------- per-graph top-k (bitonic, desc score, ties -> lower idx) ----------------
__global__ __launch_bounds__(256) void k_topk(const float* __restrict__ score, float* __restrict__ ts,
                                              int* __restrict__ newid, int* __restrict__ selmap,
                                              int n, int k){
    __shared__ float ss[512];
    __shared__ int   si[512];
    int g = blockIdx.x, t = threadIdx.x;
    for (int i = t; i < n; i += 256){ ss[i] = score[g*n + i]; si[i] = i; }
    __syncthreads();
    for (int size = 2; size <= n; size <<= 1){
        for (int stride = size >> 1; stride > 0; stride >>= 1){
            for (int i = t; i < n; i += 256){
                int j = i ^ stride;
                if (j > i){
                    bool asc = ((i & size) == 0);
                    float s1 = ss[i], s2 = ss[j];
                    int   i1 = si[i], i2 = si[j];
                    bool gt = (s1 < s2) || (s1 == s2 && i1 > i2);
                    if (gt == asc){ ss[i] = s2; ss[j] = s1; si[i] = i2; si[j] = i1; }
                }
            }
            __syncthreads();
        }
    }
    for (int r = t; r < k; r += 256){
        int old = g*n + si[r];
        int nw  = g*k + r;
        newid[old] = nw;
        selmap[nw] = old;
        ts[nw] = tanhf(ss[r]);
    }
}

// ---------------- gather pooled nodes ----------------
__global__ __launch_bounds__(256) void k_gather(const float* __restrict__ X, const int* __restrict__ selmap,
                                                const float* __restrict__ ts, float* __restrict__ Y, int Nk){
    int gid = blockIdx.x*256 + threadIdx.x;
    int v = gid >> 5, f4 = gid & 31;
    if (v >= Nk) return;
    int o = selmap[v];
    float t = ts[v];
    float4 x = *(const float4*)(X + (size_t)o*HF + f4*4);
    x.x *= t; x.y *= t; x.z *= t; x.w *= t;
    *(float4*)(Y + (size_t)v*HF + f4*4) = x;
}

// ---------------- readout: gacc[g] += [max_j h, mean_j h] ----------------
__global__ __launch_bounds__(256) void k_readout(const float* __restrict__ Y, float* __restrict__ gacc, int k){
    int f = threadIdx.x & 127, h = threadIdx.x >> 7, g = blockIdx.x;
    float mx = -3.4e38f, sm = 0.f;
    for (int j = h; j < k; j += 2){
        float x = Y[((size_t)g*k + j)*HF + f];
        mx = fmaxf(mx, x); sm += x;
    }
    __shared__ float l1[256], l2[256];
    l1[threadIdx.x] = mx; l2[threadIdx.x] = sm;
    __syncthreads();
    if (threadIdx.x < 128){
        mx = fmaxf(l1[f], l1[f+128]);
        sm = l2[f] + l2[f+128];
        gacc[g*256 + f]       += mx;
        gacc[g*256 + 128 + f] += sm / (float)k;
    }
}

// ---------------- edge remap ----------------
__global__ __launch_bounds__(256) void k_remap(int* __restrict__ src, int* __restrict__ dst,
                                               float* __restrict__ w, const int* __restrict__ newid){
    int e = blockIdx.x*256 + threadIdx.x;
    if (e >= ETOT) return;
    if (w[e] > 0.5f){
        int ns = newid[src[e]], nd = newid[dst[e]];
        if (ns >= 0 && nd >= 0){ src[e] = ns; dst[e] = nd; }
        else { src[e] = 0; dst[e] = 0; w[e] = 0.f; }
    } else { src[e] = 0; dst[e] = 0; }
}

// ---------------- head ----------------
__global__ __launch_bounds__(256) void k_lin(const float* __restrict__ in, const float* __restrict__ W,
                                             const float* __restrict__ bias, float* __restrict__ out,
                                             int K, int Ncol, float scale){
    int gid = blockIdx.x*256 + threadIdx.x;
    int r = gid / Ncol, c = gid - r*Ncol;
    float s = 0.f;
    for (int kk = 0; kk < K; ++kk) s += in[r*K + kk] * W[kk*Ncol + c];
    out[r*Ncol + c] = s*scale + bias[c];
}
__global__ void k_bn_head(float* __restrict__ t, const float* __restrict__ gw, const float* __restrict__ gb,
                          int Ncol){
    int c = threadIdx.x;
    float s = 0.f, s2 = 0.f;
    for (int r = 0; r < 128; ++r){ float x = t[r*Ncol + c]; s += x; s2 += x*x; }
    float mean = s * (1.f/128.f);
    float var  = s2 * (1.f/128.f) - mean*mean;
    float iv   = rsqrtf(var + 1e-5f);
    float ga = gw[c], be = gb[c];
    for (int r = 0; r < 128; ++r){
        float x = t[r*Ncol + c];
        t[r*Ncol + c] = fmaxf((x - mean)*iv*ga + be, 0.f);
    }
}
__global__ void k_head_out(const float* __restrict__ t2, const float* __restrict__ W,
                           const float* __restrict__ bias, float* __restrict__ out){
    int r = threadIdx.x;  // 128 rows
    float lg[10];
    float m = -3.4e38f;
    for (int j = 0; j < 10; ++j){
        float s = bias[j];
        for (int kk = 0; kk < 64; ++kk) s += t2[r*64 + kk] * W[kk*10 + j];
        lg[j] = s; m = fmaxf(m, s);
    }
    float se = 0.f;
    for (int j = 0; j < 10; ++j) se += expf(lg[j] - m);
    float l = logf(se) + m;
    for (int j = 0; j < 10; ++j) out[r*10 + j] = lg[j] - l;
}

extern "C" void kernel_launch(void* const* d_in, const int* in_sizes, int n_in,
                              void* d_out, int out_size, void* d_ws, size_t ws_size,
                              hipStream_t stream){
    const float* x     = (const float*)d_in[0];
    const float* convW = (const float*)d_in[1];
    const float* convb = (const float*)d_in[2];
    const float* bnW   = (const float*)d_in[3];
    const float* bnB   = (const float*)d_in[4];
    const float* bn7W  = (const float*)d_in[5];
    const float* bn7B  = (const float*)d_in[6];
    const float* attW  = (const float*)d_in[7];
    const float* theta = (const float*)d_in[8];
    const float* lin1W = (const float*)d_in[9];
    const float* lin1b = (const float*)d_in[10];
    const float* lin2W = (const float*)d_in[11];
    const float* lin2b = (const float*)d_in[12];
    const float* lin3W = (const float*)d_in[13];
    const float* lin3b = (const float*)d_in[14];

    char* base = (char*)d_ws;
    size_t off = 0;
    auto take = [&](size_t bytes) -> void* {
        void* p = base + off;
        off = (off + bytes + 255) & ~(size_t)255;
        return p;
    };
    float* bufA  = (float*)take((size_t)N0G*HF*4);
    float* bufB  = (float*)take((size_t)N0G*HF*4);
    float* w     = (float*)take((size_t)ETOT*4);
    int*   srcw  = (int*)  take((size_t)ETOT*4);
    int*   dstw  = (int*)  take((size_t)ETOT*4);
    int*   cnt   = (int*)  take((size_t)N0G*4);
    int*   rowp  = (int*)  take((size_t)(N0G+1)*4);
    int*   curs  = (int*)  take((size_t)N0G*4);
    float* dinv  = (float*)take((size_t)N0G*4);
    int*   csr_s = (int*)  take((size_t)ETOT*4);
    int*   psum  = (int*)  take(256*4);
    int*   boff  = (int*)  take(256*4);
    float* p0v   = (float*)take((size_t)N0G*4);
    float* p1v   = (float*)take((size_t)N0G*4);
    float* tAv   = (float*)take((size_t)N0G*4);
    float* tBv   = (float*)take((size_t)N0G*4);
    float* scv   = (float*)take((size_t)N0G*4);
    float* tsv   = (float*)take((size_t)(N0G/2)*4);
    int*   newid = (int*)  take((size_t)N0G*4);
    int*   selmap= (int*)  take((size_t)(N0G/2)*4);
    float* stats = (float*)take(256*4);
    float* gacc  = (float*)take((size_t)B_GRAPH*256*4);
    float* t1    = (float*)take((size_t)B_GRAPH*128*4);
    float* t2    = (float*)take((size_t)B_GRAPH*64*4);

    // Jacobi coefficients (A=B=1 -> c2 term is 0)
    auto coef = [](int kk, float& ca, float& cc){
        double a = 1.0, b = 1.0;
        double c0 = 2.0*kk*(kk+a+b)*(2.0*kk+a+b-2.0);
        double c1 = (2.0*kk+a+b-1.0)*(2.0*kk+a+b)*(2.0*kk+a+b-2.0);
        double c3 = 2.0*(kk+a-1.0)*(kk+b-1.0)*(2.0*kk+a+b);
        ca = (float)(c1/c0); cc = (float)(-c3/c0);
    };
    float ca2, cc2, ca3, cc3;
    coef(2, ca2, cc2);
    coef(3, ca3, cc3);

    hipMemcpyAsync(srcw, d_in[15], (size_t)ETOT*4, hipMemcpyDeviceToDevice, stream);
    hipMemcpyAsync(dstw, d_in[16], (size_t)ETOT*4, hipMemcpyDeviceToDevice, stream);
    k_fill1<<<ETOT/256, 256, 0, stream>>>(w, ETOT);
    hipMemsetAsync(gacc, 0, (size_t)B_GRAPH*256*4, stream);

    for (int i = 0; i < 5; ++i){
        int n = 512 >> i, k = n >> 1;
        int Nn = B_GRAPH*n, Nk = B_GRAPH*k;
        int nb = Nn/256;
        float* hin = (i & 1) ? bufB : bufA;
        float* tmp = (i & 1) ? bufA : bufB;
        const float* gemmA = (i == 0) ? x : hin;   // level 0 reads x directly

        hipMemsetAsync(cnt, 0, (size_t)Nn*4, stream);
        k_hist<<<ETOT/256, 256, 0, stream>>>(dstw, w, cnt);
        k_part<<<nb, 256, 0, stream>>>(cnt, psum);
        k_mid<<<1, 256, 0, stream>>>(psum, boff, rowp, nb, Nn);
        k_final<<<nb, 256, 0, stream>>>(cnt, boff, rowp, dinv, curs);
        k_scatter<<<ETOT/256, 256, 0, stream>>>(srcw, dstw, w, curs, csr_s);

        k_gemm<<<Nn/64, 256, 0, stream>>>(gemmA, convW + (size_t)i*HF*HF, tmp);
        k_prop<<<(Nn*32)/256, 256, 0, stream>>>(tmp, convb + i*HF, rowp, csr_s, dinv, hin, Nn);

        hipMemsetAsync(stats, 0, 256*4, stream);
        k_bnstats<<<Nn/256, 256, 0, stream>>>(hin, stats);
        k_bn_s0<<<Nn/2, 256, 0, stream>>>(hin, bnW + i*HF, bnB + i*HF, attW + i*HF, stats, p0v, 1.0f/(float)Nn);

        // Jacobi: t0=pvec(p0); p1=2*t0, t1=pvec(p1); fused: p2=ca2*t1+cc2*p0, t2=pvec(p2), p3, score
        k_pvec<<<Nn/256, 256, 0, stream>>>(p0v, p0v, rowp, csr_s, dinv, tAv, scv, 1.0f, 0.0f, Nn);
        k_pvec<<<Nn/256, 256, 0, stream>>>(tAv, p0v, rowp, csr_s, dinv, tBv, p1v, 2.0f, 0.0f, Nn);
        k_pvec_score<<<Nn/256, 256, 0, stream>>>(tBv, p0v, p1v, rowp, csr_s, dinv, theta + i*4, scv,
                                                 ca2, cc2, ca3, cc3, Nn);

        hipMemsetAsync(newid, 0xFF, (size_t)Nn*4, stream);   // -1
        k_topk<<<B_GRAPH, 256, 0, stream>>>(scv, tsv, newid, selmap, n, k);
        k_gather<<<(Nk*32)/256, 256, 0, stream>>>(hin, selmap, tsv, tmp, Nk);
        k_readout<<<B_GRAPH, 256, 0, stream>>>(tmp, gacc, k);
        k_remap<<<ETOT/256, 256, 0, stream>>>(srcw, dstw, w, newid);
    }

    k_lin<<<(B_GRAPH*128)/256, 256, 0, stream>>>(gacc, lin1W, lin1b, t1, 256, 128, 0.2f);
    k_bn_head<<<1, 128, 0, stream>>>(t1, bnW + 5*HF, bnB + 5*HF, 128);
    k_lin<<<(B_GRAPH*64)/256, 256, 0, stream>>>(t1, lin2W, lin2b, t2, 128, 64, 1.0f);
    k_bn_head<<<1, 64, 0, stream>>>(t2, bn7W, bn7B, 64);
    k_head_out<<<1, 128, 0, stream>>>(t2, lin3W, lin3b, (float*)d_out);
}

// Round 4
// 863.026 us; speedup vs baseline: 1.3396x; 1.1479x over previous
//
#include <hip/hip_runtime.h>
#include <hip/hip_bf16.h>

#define B_GRAPH 128
#define ETOT    (128*4096)   // 524288 edges (static)
#define N0G     (128*512)    // 65536 nodes at level 0
#define HF      128

// ---------------- init ----------------
__global__ __launch_bounds__(256) void k_fill1(float* w, int n){
    int i = blockIdx.x*256 + threadIdx.x;
    if (i < n) w[i] = 1.0f;
}

// ---------------- CSR build ----------------
__global__ __launch_bounds__(256) void k_hist(const int* __restrict__ dst, const float* __restrict__ w,
                                              int* __restrict__ cnt){
    int e = blockIdx.x*256 + threadIdx.x;
    if (e < ETOT && w[e] > 0.5f) atomicAdd(&cnt[dst[e]], 1);
}

// two-level scan: k_part (per-block sums) -> k_mid (scan of partials) -> k_final (block scan + dinv/cursor)
__global__ __launch_bounds__(256) void k_part(const int* __restrict__ cnt, int* __restrict__ psum){
    __shared__ int red[256];
    int t = threadIdx.x;
    red[t] = cnt[blockIdx.x*256 + t];
    __syncthreads();
    for (int off = 128; off; off >>= 1){
        if (t < off) red[t] += red[t + off];
        __syncthreads();
    }
    if (t == 0) psum[blockIdx.x] = red[0];
}
__global__ __launch_bounds__(256) void k_mid(const int* __restrict__ psum, int* __restrict__ boff,
                                             int* __restrict__ rowptr, int nb, int Nn){
    __shared__ int s[256];
    int t = threadIdx.x;
    int v = (t < nb) ? psum[t] : 0;
    s[t] = v;
    __syncthreads();
    for (int off = 1; off < 256; off <<= 1){
        int a = (t >= off) ? s[t-off] : 0;
        __syncthreads();
        s[t] += a;
        __syncthreads();
    }
    if (t < nb) boff[t] = s[t] - v;       // exclusive block offset
    if (t == nb-1) rowptr[Nn] = s[t];     // total
}
__global__ __launch_bounds__(256) void k_final(const int* __restrict__ cnt, const int* __restrict__ boff,
                                               int* __restrict__ rowptr, float* __restrict__ dinv,
                                               int* __restrict__ cursor){
    __shared__ int s[256];
    int t = threadIdx.x, i = blockIdx.x*256 + t;
    int c = cnt[i];
    s[t] = c;
    __syncthreads();
    for (int off = 1; off < 256; off <<= 1){
        int a = (t >= off) ? s[t-off] : 0;
        __syncthreads();
        s[t] += a;
        __syncthreads();
    }
    int rp = boff[blockIdx.x] + s[t] - c;  // exclusive prefix
    rowptr[i] = rp;
    cursor[i] = rp;
    dinv[i]   = rsqrtf((float)c + 1.0f);
}

__global__ __launch_bounds__(256) void k_scatter(const int* __restrict__ src, const int* __restrict__ dst,
                                                 const float* __restrict__ w, const float* __restrict__ dinv,
                                                 int* __restrict__ cursor, int* __restrict__ csr_s,
                                                 float* __restrict__ csr_e){
    int e = blockIdx.x*256 + threadIdx.x;
    if (e < ETOT && w[e] > 0.5f){
        int sN = src[e], d = dst[e];
        int p = atomicAdd(&cursor[d], 1);
        csr_s[p] = sN;
        csr_e[p] = dinv[sN];
    }
}

// ---------------- GEMM: C[N,128] = A[N,128] @ W[128,128] (all fp32) ----------------
__global__ __launch_bounds__(256) void k_gemm(const float* __restrict__ A, const float* __restrict__ Wg,
                                              float* __restrict__ C){
    __shared__ float Ws[HF*HF];
    for (int i = threadIdx.x; i < HF*HF; i += 256) Ws[i] = Wg[i];
    __syncthreads();
    int m0 = blockIdx.x * 64;
    int tx = threadIdx.x & 15, ty = threadIdx.x >> 4;
    int r0 = m0 + ty*4, c0 = tx*8;
    float acc[4][8];
    #pragma unroll
    for (int j=0;j<4;++j)
        #pragma unroll
        for (int l=0;l<8;++l) acc[j][l] = 0.f;
    for (int k4 = 0; k4 < 32; ++k4){
        float4 av[4];
        #pragma unroll
        for (int j=0;j<4;++j)
            av[j] = *(const float4*)(A + (size_t)(r0+j)*HF + k4*4);
        #pragma unroll
        for (int kk=0; kk<4; ++kk){
            const float* wr = Ws + (k4*4+kk)*HF + c0;
            float bv[8];
            #pragma unroll
            for (int l=0;l<8;++l) bv[l] = wr[l];
            #pragma unroll
            for (int j=0;j<4;++j){
                float a = reinterpret_cast<const float*>(&av[j])[kk];
                #pragma unroll
                for (int l=0;l<8;++l) acc[j][l] += a*bv[l];
            }
        }
    }
    #pragma unroll
    for (int j=0;j<4;++j){
        float4 o0 = make_float4(acc[j][0],acc[j][1],acc[j][2],acc[j][3]);
        float4 o1 = make_float4(acc[j][4],acc[j][5],acc[j][6],acc[j][7]);
        *(float4*)(C + (size_t)(r0+j)*HF + c0)     = o0;
        *(float4*)(C + (size_t)(r0+j)*HF + c0 + 4) = o1;
    }
}

// ---------------- prop: X[v] = Y[v]*dv*dv + dv * sum_e dinv[s]*Y[s] + convb ----------------
__global__ __launch_bounds__(256) void k_prop(const float* __restrict__ Y, const float* __restrict__ cb,
                                              const int* __restrict__ rowptr, const int* __restrict__ cs,
                                              const float* __restrict__ ce, const float* __restrict__ dinv,
                                              float* __restrict__ X, int Nn){
    int gid = blockIdx.x*256 + threadIdx.x;
    int v = gid >> 5, f4 = gid & 31;
    if (v >= Nn) return;
    float dv = dinv[v];
    float4 y = *(const float4*)(Y + (size_t)v*HF + f4*4);
    float4 acc = make_float4(0.f, 0.f, 0.f, 0.f);
    int e1 = rowptr[v+1];
    for (int j = rowptr[v]; j < e1; ++j){
        int s = cs[j] & (Nn - 1);       // Nn is a power of two; mask = OOB insurance
        float en = ce[j];
        float4 h = *(const float4*)(Y + (size_t)s*HF + f4*4);
        acc.x += en*h.x; acc.y += en*h.y; acc.z += en*h.z; acc.w += en*h.w;
    }
    int f = f4*4;
    acc.x = y.x*dv*dv + dv*acc.x + cb[f];
    acc.y = y.y*dv*dv + dv*acc.y + cb[f+1];
    acc.z = y.z*dv*dv + dv*acc.z + cb[f+2];
    acc.w = y.w*dv*dv + dv*acc.w + cb[f+3];
    *(float4*)(X + (size_t)v*HF + f) = acc;
}

// ---------------- BN stats (sum, sumsq per column) ----------------
__global__ __launch_bounds__(256) void k_bnstats(const float* __restrict__ X, float* __restrict__ stats){
    int c = threadIdx.x & 127, h = threadIdx.x >> 7;
    int r0 = blockIdx.x * 256;
    float s = 0.f, s2 = 0.f;
    for (int r = r0 + h; r < r0 + 256; r += 2){
        float x = X[(size_t)r*HF + c];
        s += x; s2 += x*x;
    }
    __shared__ float l1[256], l2[256];
    l1[threadIdx.x] = s; l2[threadIdx.x] = s2;
    __syncthreads();
    if (threadIdx.x < 128){
        atomicAdd(&stats[c],     l1[threadIdx.x] + l1[threadIdx.x+128]);
        atomicAdd(&stats[128+c], l2[threadIdx.x] + l2[threadIdx.x+128]);
    }
}

// ---------------- BN apply + ReLU + s0 = h @ attW ----------------
__global__ __launch_bounds__(256) void k_bn_s0(float* __restrict__ X, const float* __restrict__ gw,
                                               const float* __restrict__ gb, const float* __restrict__ aw,
                                               const float* __restrict__ stats, float* __restrict__ p0,
                                               float invN){
    int f = threadIdx.x & 127, rl = threadIdx.x >> 7;
    int r = blockIdx.x*2 + rl;
    float mean = stats[f]*invN;
    float var  = stats[128+f]*invN - mean*mean;
    float iv   = rsqrtf(var + 1e-5f);
    float x = X[(size_t)r*HF + f];
    float val = (x - mean)*iv*gw[f] + gb[f];
    val = fmaxf(val, 0.f);
    X[(size_t)r*HF + f] = val;
    __shared__ float red[256];
    red[threadIdx.x] = val * aw[f];
    __syncthreads();
    for (int off = 64; off; off >>= 1){
        if (f < off) red[threadIdx.x] += red[threadIdx.x + off];
        __syncthreads();
    }
    if (f == 0) p0[r] = red[rl << 7];
}

// ---------------- fused Jacobi step: p_new = ca*tin + cc*prev ; out_t = pvec(p_new) ----------------
__global__ __launch_bounds__(256) void k_pvec(const float* __restrict__ tin, const float* __restrict__ prev,
                                              const int* __restrict__ rowptr, const int* __restrict__ cs,
                                              const float* __restrict__ ce, const float* __restrict__ dinv,
                                              float* __restrict__ outt, float* __restrict__ outp,
                                              float ca, float cc, int Nn){
    int v = blockIdx.x*256 + threadIdx.x;
    if (v >= Nn) return;
    float pv = ca*tin[v] + cc*prev[v];
    outp[v] = pv;
    float dv = dinv[v];
    float acc = 0.f;
    int e1 = rowptr[v+1];
    for (int j = rowptr[v]; j < e1; ++j){
        int s = cs[j] & (Nn - 1);
        float ps = ca*tin[s] + cc*prev[s];
        acc += ce[j]*ps;
    }
    outt[v] = pv*dv*dv + dv*acc;
}
// last Jacobi step + theta combine fused (p3 needs only thread-local t2)
__global__ __launch_bounds__(256) void k_pvec_score(const float* __restrict__ tin,  // t1
                                                    const float* __restrict__ prev, // p0
                                                    const float* __restrict__ p1,
                                                    const int* __restrict__ rowptr, const int* __restrict__ cs,
                                                    const float* __restrict__ ce, const float* __restrict__ dinv,
                                                    const float* __restrict__ th, float* __restrict__ score,
                                                    float ca2, float cc2, float ca3, float cc3, int Nn){
    int v = blockIdx.x*256 + threadIdx.x;
    if (v >= Nn) return;
    float p2 = ca2*tin[v] + cc2*prev[v];
    float dv = dinv[v];
    float acc = 0.f;
    int e1 = rowptr[v+1];
    for (int j = rowptr[v]; j < e1; ++j){
        int s = cs[j] & (Nn - 1);
        acc += ce[j]*(ca2*tin[s] + cc2*prev[s]);
    }
    float t2 = p2*dv*dv + dv*acc;
    float p3 = ca3*t2 + cc3*p1[v];
    score[v] = th[0]*prev[v] + th[1]*p1[v] + th[2]*p2 + th[3]*p3;
}

// ---------------- per-graph top-k (bitonic, desc score, ties -> lower idx) ----------------
__global__ __launch_bounds__(256) void k_topk(const float* __restrict__ score, float* __restrict__ ts,
                                              int* __restrict__ newid, int* __restrict__ selmap,
                                              int n, int k){
    __shared__ float ss[512];
    __shared__ int   si[512];
    int g = blockIdx.x, t = threadIdx.x;
    for (int i = t; i < n; i += 256){ ss[i] = score[g*n + i]; si[i] = i; }
    __syncthreads();
    for (int size = 2; size <= n; size <<= 1){
        for (int stride = size >> 1; stride > 0; stride >>= 1){
            for (int i = t; i < n; i += 256){
                int j = i ^ stride;
                if (j > i){
                    bool asc = ((i & size) == 0);
                    float s1 = ss[i], s2 = ss[j];
                    int   i1 = si[i], i2 = si[j];
                    bool gt = (s1 < s2) || (s1 == s2 && i1 > i2);
                    if (gt == asc){ ss[i] = s2; ss[j] = s1; si[i] = i2; si[j] = i1; }
                }
            }
            __syncthreads();
        }
    }
    for (int r = t; r < k; r += 256){
        int old = g*n + si[r];
        int nw  = g*k + r;
        newid[old] = nw;
        selmap[nw] = old;
        ts[nw] = tanhf(ss[r]);
    }
}

// ---------------- gather pooled nodes ----------------
__global__ __launch_bounds__(256) void k_gather(const float* __restrict__ X, const int* __restrict__ selmap,
                                                const float* __restrict__ ts, float* __restrict__ Y, int Nk){
    int gid = blockIdx.x*256 + threadIdx.x;
    int v = gid >> 5, f4 = gid & 31;
    if (v >= Nk) return;
    int o = selmap[v];
    float t = ts[v];
    float4 x = *(const float4*)(X + (size_t)o*HF + f4*4);
    x.x *= t; x.y *= t; x.z *= t; x.w *= t;
    *(float4*)(Y + (size_t)v*HF + f4*4) = x;
}

// ---------------- readout: gacc[g] += [max_j h, mean_j h] ----------------
__global__ __launch_bounds__(256) void k_readout(const float* __restrict__ Y, float* __restrict__ gacc, int k){
    int f = threadIdx.x & 127, h = threadIdx.x >> 7, g = blockIdx.x;
    float mx = -3.4e38f, sm = 0.f;
    for (int j = h; j < k; j += 2){
        float x = Y[((size_t)g*k + j)*HF + f];
        mx = fmaxf(mx, x); sm += x;
    }
    __shared__ float l1[256], l2[256];
    l1[threadIdx.x] = mx; l2[threadIdx.x] = sm;
    __syncthreads();
    if (threadIdx.x < 128){
        mx = fmaxf(l1[f], l1[f+128]);
        sm = l2[f] + l2[f+128];
        gacc[g*256 + f]       += mx;
        gacc[g*256 + 128 + f] += sm / (float)k;
    }
}

// ---------------- edge remap ----------------
__global__ __launch_bounds__(256) void k_remap(int* __restrict__ src, int* __restrict__ dst,
                                               float* __restrict__ w, const int* __restrict__ newid){
    int e = blockIdx.x*256 + threadIdx.x;
    if (e >= ETOT) return;
    if (w[e] > 0.5f){
        int ns = newid[src[e]], nd = newid[dst[e]];
        if (ns >= 0 && nd >= 0){ src[e] = ns; dst[e] = nd; }
        else { src[e] = 0; dst[e] = 0; w[e] = 0.f; }
    } else { src[e] = 0; dst[e] = 0; }
}

// ---------------- head (parallel, fully unrolled) ----------------
// H1: t1[128x128] = gacc[128x256] @ W1 * 0.2 + b1 ; atomic col stats into sh[0:128],sh[128:256]
__global__ __launch_bounds__(256) void k_head1(const float* __restrict__ gacc, const float* __restrict__ W1,
                                               const float* __restrict__ b1, float* __restrict__ t1,
                                               float* __restrict__ sh){
    int r = blockIdx.x;
    int c = threadIdx.x & 127, h = threadIdx.x >> 7;
    __shared__ float gs[256];
    __shared__ float red[256];
    gs[threadIdx.x] = gacc[r*256 + threadIdx.x];
    __syncthreads();
    float s = 0.f;
    #pragma unroll
    for (int kk = 0; kk < 128; ++kk)
        s += gs[h*128 + kk] * W1[(h*128 + kk)*128 + c];
    red[threadIdx.x] = s;
    __syncthreads();
    if (h == 0){
        float v = (red[c] + red[c+128]) * 0.2f + b1[c];
        t1[r*128 + c] = v;
        atomicAdd(&sh[c], v);
        atomicAdd(&sh[128 + c], v*v);
    }
}
// H2: BN(t1)+ReLU -> t2[128x64] = @W2 + b2 ; atomic stats into sh[256:320],sh[320:384]
__global__ __launch_bounds__(128) void k_head2(const float* __restrict__ t1, const float* __restrict__ gw,
                                               const float* __restrict__ gb, const float* __restrict__ W2,
                                               const float* __restrict__ b2, float* __restrict__ sh,
                                               float* __restrict__ t2){
    int r = blockIdx.x, t = threadIdx.x;
    int cc = t & 63, h = t >> 6;
    __shared__ float row[128];
    __shared__ float red[128];
    {
        float mean = sh[t] * (1.f/128.f);
        float var  = sh[128+t]*(1.f/128.f) - mean*mean;
        float iv   = rsqrtf(var + 1e-5f);
        float v = (t1[r*128+t] - mean)*iv*gw[t] + gb[t];
        row[t] = fmaxf(v, 0.f);
    }
    __syncthreads();
    float s = 0.f;
    #pragma unroll
    for (int kk = 0; kk < 64; ++kk)
        s += row[h*64+kk] * W2[(h*64+kk)*64 + cc];
    red[t] = s;
    __syncthreads();
    if (h == 0){
        float v = red[cc] + red[cc+64] + b2[cc];
        t2[r*64+cc] = v;
        atomicAdd(&sh[256+cc], v);
        atomicAdd(&sh[320+cc], v*v);
    }
}
// H3: BN(t2)+ReLU -> logits = @W3 + b3 -> log_softmax
__global__ __launch_bounds__(64) void k_head3(const float* __restrict__ t2, const float* __restrict__ gw,
                                              const float* __restrict__ gb, const float* __restrict__ W3,
                                              const float* __restrict__ b3, const float* __restrict__ sh,
                                              float* __restrict__ out){
    int r = blockIdx.x, t = threadIdx.x;  // 64 threads = 1 wave
    float mean = sh[256+t]*(1.f/128.f);
    float var  = sh[320+t]*(1.f/128.f) - mean*mean;
    float iv   = rsqrtf(var + 1e-5f);
    float v = fmaxf((t2[r*64+t]-mean)*iv*gw[t] + gb[t], 0.f);
    float lg[10];
    #pragma unroll
    for (int j = 0; j < 10; ++j){
        float p = v * W3[t*10 + j];
        for (int off = 32; off; off >>= 1) p += __shfl_down(p, off);
        lg[j] = p;
    }
    if (t == 0){
        float m = -3.4e38f;
        #pragma unroll
        for (int j = 0; j < 10; ++j){ lg[j] += b3[j]; m = fmaxf(m, lg[j]); }
        float se = 0.f;
        #pragma unroll
        for (int j = 0; j < 10; ++j) se += expf(lg[j] - m);
        float l = logf(se) + m;
        #pragma unroll
        for (int j = 0; j < 10; ++j) out[r*10 + j] = lg[j] - l;
    }
}

extern "C" void kernel_launch(void* const* d_in, const int* in_sizes, int n_in,
                              void* d_out, int out_size, void* d_ws, size_t ws_size,
                              hipStream_t stream){
    const float* x     = (const float*)d_in[0];
    const float* convW = (const float*)d_in[1];
    const float* convb = (const float*)d_in[2];
    const float* bnW   = (const float*)d_in[3];
    const float* bnB   = (const float*)d_in[4];
    const float* bn7W  = (const float*)d_in[5];
    const float* bn7B  = (const float*)d_in[6];
    const float* attW  = (const float*)d_in[7];
    const float* theta = (const float*)d_in[8];
    const float* lin1W = (const float*)d_in[9];
    const float* lin1b = (const float*)d_in[10];
    const float* lin2W = (const float*)d_in[11];
    const float* lin2b = (const float*)d_in[12];
    const float* lin3W = (const float*)d_in[13];
    const float* lin3b = (const float*)d_in[14];

    char* base = (char*)d_ws;
    size_t off = 0;
    auto take = [&](size_t bytes) -> void* {
        void* p = base + off;
        off = (off + bytes + 255) & ~(size_t)255;
        return p;
    };
    float* bufA  = (float*)take((size_t)N0G*HF*4);
    float* bufB  = (float*)take((size_t)N0G*HF*4);
    float* w     = (float*)take((size_t)ETOT*4);
    int*   srcw  = (int*)  take((size_t)ETOT*4);
    int*   dstw  = (int*)  take((size_t)ETOT*4);
    int*   cnt   = (int*)  take((size_t)N0G*4);
    int*   rowp  = (int*)  take((size_t)(N0G+1)*4);
    int*   curs  = (int*)  take((size_t)N0G*4);
    float* dinv  = (float*)take((size_t)N0G*4);
    int*   csr_s = (int*)  take((size_t)ETOT*4);
    float* csr_e = (float*)take((size_t)ETOT*4);
    int*   psum  = (int*)  take(256*4);
    int*   boff  = (int*)  take(256*4);
    float* p0v   = (float*)take((size_t)N0G*4);
    float* p1v   = (float*)take((size_t)N0G*4);
    float* tAv   = (float*)take((size_t)N0G*4);
    float* tBv   = (float*)take((size_t)N0G*4);
    float* scv   = (float*)take((size_t)N0G*4);
    float* tsv   = (float*)take((size_t)(N0G/2)*4);
    int*   newid = (int*)  take((size_t)N0G*4);
    int*   selmap= (int*)  take((size_t)(N0G/2)*4);
    float* stats = (float*)take(256*4);
    float* gacc  = (float*)take((size_t)B_GRAPH*256*4);
    float* t1    = (float*)take((size_t)B_GRAPH*128*4);
    float* t2    = (float*)take((size_t)B_GRAPH*64*4);
    float* statsH= (float*)take(384*4);

    // Jacobi coefficients (A=B=1 -> c2 term is 0)
    auto coef = [](int kk, float& ca, float& cc){
        double a = 1.0, b = 1.0;
        double c0 = 2.0*kk*(kk+a+b)*(2.0*kk+a+b-2.0);
        double c1 = (2.0*kk+a+b-1.0)*(2.0*kk+a+b)*(2.0*kk+a+b-2.0);
        double c3 = 2.0*(kk+a-1.0)*(kk+b-1.0)*(2.0*kk+a+b);
        ca = (float)(c1/c0); cc = (float)(-c3/c0);
    };
    float ca2, cc2, ca3, cc3;
    coef(2, ca2, cc2);
    coef(3, ca3, cc3);

    hipMemcpyAsync(srcw, d_in[15], (size_t)ETOT*4, hipMemcpyDeviceToDevice, stream);
    hipMemcpyAsync(dstw, d_in[16], (size_t)ETOT*4, hipMemcpyDeviceToDevice, stream);
    k_fill1<<<ETOT/256, 256, 0, stream>>>(w, ETOT);
    hipMemsetAsync(gacc, 0, (size_t)B_GRAPH*256*4, stream);

    for (int i = 0; i < 5; ++i){
        int n = 512 >> i, k = n >> 1;
        int Nn = B_GRAPH*n, Nk = B_GRAPH*k;
        int nb = Nn/256;
        float* hin = (i & 1) ? bufB : bufA;
        float* tmp = (i & 1) ? bufA : bufB;
        const float* gemmA = (i == 0) ? x : hin;   // level 0 reads x directly

        hipMemsetAsync(cnt, 0, (size_t)Nn*4, stream);
        k_hist<<<ETOT/256, 256, 0, stream>>>(dstw, w, cnt);
        k_part<<<nb, 256, 0, stream>>>(cnt, psum);
        k_mid<<<1, 256, 0, stream>>>(psum, boff, rowp, nb, Nn);
        k_final<<<nb, 256, 0, stream>>>(cnt, boff, rowp, dinv, curs);
        k_scatter<<<ETOT/256, 256, 0, stream>>>(srcw, dstw, w, dinv, curs, csr_s, csr_e);

        k_gemm<<<Nn/64, 256, 0, stream>>>(gemmA, convW + (size_t)i*HF*HF, tmp);
        k_prop<<<(Nn*32)/256, 256, 0, stream>>>(tmp, convb + i*HF, rowp, csr_s, csr_e, dinv, hin, Nn);

        hipMemsetAsync(stats, 0, 256*4, stream);
        k_bnstats<<<Nn/256, 256, 0, stream>>>(hin, stats);
        k_bn_s0<<<Nn/2, 256, 0, stream>>>(hin, bnW + i*HF, bnB + i*HF, attW + i*HF, stats, p0v, 1.0f/(float)Nn);

        // Jacobi: t0=pvec(p0); p1=2*t0, t1=pvec(p1); fused: p2=ca2*t1+cc2*p0, t2=pvec(p2), p3, score
        k_pvec<<<Nn/256, 256, 0, stream>>>(p0v, p0v, rowp, csr_s, csr_e, dinv, tAv, scv, 1.0f, 0.0f, Nn);
        k_pvec<<<Nn/256, 256, 0, stream>>>(tAv, p0v, rowp, csr_s, csr_e, dinv, tBv, p1v, 2.0f, 0.0f, Nn);
        k_pvec_score<<<Nn/256, 256, 0, stream>>>(tBv, p0v, p1v, rowp, csr_s, csr_e, dinv, theta + i*4, scv,
                                                 ca2, cc2, ca3, cc3, Nn);

        hipMemsetAsync(newid, 0xFF, (size_t)Nn*4, stream);   // -1
        k_topk<<<B_GRAPH, 256, 0, stream>>>(scv, tsv, newid, selmap, n, k);
        k_gather<<<(Nk*32)/256, 256, 0, stream>>>(hin, selmap, tsv, tmp, Nk);
        k_readout<<<B_GRAPH, 256, 0, stream>>>(tmp, gacc, k);
        k_remap<<<ETOT/256, 256, 0, stream>>>(srcw, dstw, w, newid);
    }

    hipMemsetAsync(statsH, 0, 384*4, stream);
    k_head1<<<B_GRAPH, 256, 0, stream>>>(gacc, lin1W, lin1b, t1, statsH);
    k_head2<<<B_GRAPH, 128, 0, stream>>>(t1, bnW + 5*HF, bnB + 5*HF, lin2W, lin2b, statsH, t2);
    k_head3<<<B_GRAPH, 64, 0, stream>>>(t2, bn7W, bn7B, lin3W, lin3b, statsH, (float*)d_out);
}

// Round 5
// 850.778 us; speedup vs baseline: 1.3589x; 1.0144x over previous
//
#include <hip/hip_runtime.h>
#include <hip/hip_bf16.h>

#define B_GRAPH 128
#define ETOT    (128*4096)   // 524288 edges (static)
#define N0G     (128*512)    // 65536 nodes at level 0
#define HF      128

// ---------------- init ----------------
__global__ __launch_bounds__(256) void k_fill1(float* w, int n){
    int i = blockIdx.x*256 + threadIdx.x;
    if (i < n) w[i] = 1.0f;
}

// ---------------- CSR build ----------------
__global__ __launch_bounds__(256) void k_hist(const int* __restrict__ dst, const float* __restrict__ w,
                                              int* __restrict__ cnt){
    int e = blockIdx.x*256 + threadIdx.x;
    if (e < ETOT && w[e] > 0.5f) atomicAdd(&cnt[dst[e]], 1);
}

// two-level scan: k_part (per-block sums) -> k_mid (scan of partials) -> k_final (block scan + dinv/cursor)
__global__ __launch_bounds__(256) void k_part(const int* __restrict__ cnt, int* __restrict__ psum){
    __shared__ int red[256];
    int t = threadIdx.x;
    red[t] = cnt[blockIdx.x*256 + t];
    __syncthreads();
    for (int off = 128; off; off >>= 1){
        if (t < off) red[t] += red[t + off];
        __syncthreads();
    }
    if (t == 0) psum[blockIdx.x] = red[0];
}
__global__ __launch_bounds__(256) void k_mid(const int* __restrict__ psum, int* __restrict__ boff,
                                             int* __restrict__ rowptr, int nb, int Nn){
    __shared__ int s[256];
    int t = threadIdx.x;
    int v = (t < nb) ? psum[t] : 0;
    s[t] = v;
    __syncthreads();
    for (int off = 1; off < 256; off <<= 1){
        int a = (t >= off) ? s[t-off] : 0;
        __syncthreads();
        s[t] += a;
        __syncthreads();
    }
    if (t < nb) boff[t] = s[t] - v;       // exclusive block offset
    if (t == nb-1) rowptr[Nn] = s[t];     // total
}
__global__ __launch_bounds__(256) void k_final(const int* __restrict__ cnt, const int* __restrict__ boff,
                                               int* __restrict__ rowptr, float* __restrict__ dinv,
                                               int* __restrict__ cursor){
    __shared__ int s[256];
    int t = threadIdx.x, i = blockIdx.x*256 + t;
    int c = cnt[i];
    s[t] = c;
    __syncthreads();
    for (int off = 1; off < 256; off <<= 1){
        int a = (t >= off) ? s[t-off] : 0;
        __syncthreads();
        s[t] += a;
        __syncthreads();
    }
    int rp = boff[blockIdx.x] + s[t] - c;  // exclusive prefix
    rowptr[i] = rp;
    cursor[i] = rp;
    dinv[i]   = rsqrtf((float)c + 1.0f);
}

// pack (src, dinv[src]) per edge -> one dwordx2 load in the gather loops
__global__ __launch_bounds__(256) void k_scatter(const int* __restrict__ src, const int* __restrict__ dst,
                                                 const float* __restrict__ w, const float* __restrict__ dinv,
                                                 int* __restrict__ cursor, int2* __restrict__ csr_p){
    int e = blockIdx.x*256 + threadIdx.x;
    if (e < ETOT && w[e] > 0.5f){
        int sN = src[e], d = dst[e];
        int p = atomicAdd(&cursor[d], 1);
        csr_p[p] = make_int2(sN, __float_as_int(dinv[sN]));
    }
}

// ---------------- GEMM: C[N,128] = A[N,128] @ W[128,128] (all fp32) ----------------
// cols per thread: {4tx..4tx+3, 4tx+64..4tx+67} -> ds_read_b128 with 2-way bank aliasing (free)
__global__ __launch_bounds__(256) void k_gemm(const float* __restrict__ A, const float* __restrict__ Wg,
                                              float* __restrict__ C){
    __shared__ float Ws[HF*HF];
    {
        float4* d4 = (float4*)Ws;
        const float4* s4 = (const float4*)Wg;
        for (int i = threadIdx.x; i < HF*HF/4; i += 256) d4[i] = s4[i];
    }
    __syncthreads();
    int m0 = blockIdx.x * 64;
    int tx = threadIdx.x & 15, ty = threadIdx.x >> 4;
    int r0 = m0 + ty*4, c0 = tx*4;
    float acc[4][8];
    #pragma unroll
    for (int j=0;j<4;++j)
        #pragma unroll
        for (int l=0;l<8;++l) acc[j][l] = 0.f;
    for (int k4 = 0; k4 < 32; ++k4){
        float4 av[4];
        #pragma unroll
        for (int j=0;j<4;++j)
            av[j] = *(const float4*)(A + (size_t)(r0+j)*HF + k4*4);
        #pragma unroll
        for (int kk=0; kk<4; ++kk){
            int k = k4*4 + kk;
            float4 w0 = *(const float4*)(Ws + k*HF + c0);
            float4 w1 = *(const float4*)(Ws + k*HF + c0 + 64);
            #pragma unroll
            for (int j=0;j<4;++j){
                float a = reinterpret_cast<const float*>(&av[j])[kk];
                acc[j][0] += a*w0.x; acc[j][1] += a*w0.y; acc[j][2] += a*w0.z; acc[j][3] += a*w0.w;
                acc[j][4] += a*w1.x; acc[j][5] += a*w1.y; acc[j][6] += a*w1.z; acc[j][7] += a*w1.w;
            }
        }
    }
    #pragma unroll
    for (int j=0;j<4;++j){
        *(float4*)(C + (size_t)(r0+j)*HF + c0)      = make_float4(acc[j][0],acc[j][1],acc[j][2],acc[j][3]);
        *(float4*)(C + (size_t)(r0+j)*HF + c0 + 64) = make_float4(acc[j][4],acc[j][5],acc[j][6],acc[j][7]);
    }
}

// ---------------- prop: X[v] = Y[v]*dv*dv + dv * sum_e dinv[s]*Y[s] + convb ----------------
// XCD-locality swizzle: all blocks of one graph land on one XCD slot (bid % 8 heuristic)
__global__ __launch_bounds__(256) void k_prop(const float* __restrict__ Y, const float* __restrict__ cb,
                                              const int* __restrict__ rowptr, const int2* __restrict__ cp,
                                              const float* __restrict__ dinv,
                                              float* __restrict__ X, int n, int lb, int Nn){
    int xcd = blockIdx.x & 7, c = blockIdx.x >> 3;
    int g = xcd*16 + (c >> lb);            // 16 graphs per XCD slot
    int m = c & ((1 << lb) - 1);           // block within graph
    int v = g*n + m*8 + (threadIdx.x >> 5);
    int f4 = threadIdx.x & 31;
    float dv = dinv[v];
    float4 y = *(const float4*)(Y + (size_t)v*HF + f4*4);
    float4 acc = make_float4(0.f, 0.f, 0.f, 0.f);
    int e1 = rowptr[v+1];
    for (int j = rowptr[v]; j < e1; ++j){
        int2 e = cp[j];
        int s = e.x & (Nn - 1);            // OOB insurance (Nn pow2)
        float en = __int_as_float(e.y);
        float4 h = *(const float4*)(Y + (size_t)s*HF + f4*4);
        acc.x += en*h.x; acc.y += en*h.y; acc.z += en*h.z; acc.w += en*h.w;
    }
    int f = f4*4;
    acc.x = y.x*dv*dv + dv*acc.x + cb[f];
    acc.y = y.y*dv*dv + dv*acc.y + cb[f+1];
    acc.z = y.z*dv*dv + dv*acc.z + cb[f+2];
    acc.w = y.w*dv*dv + dv*acc.w + cb[f+3];
    *(float4*)(X + (size_t)v*HF + f) = acc;
}

// ---------------- BN stats (sum, sumsq per column) ----------------
__global__ __launch_bounds__(256) void k_bnstats(const float* __restrict__ X, float* __restrict__ stats){
    int c = threadIdx.x & 127, h = threadIdx.x >> 7;
    int r0 = blockIdx.x * 256;
    float s = 0.f, s2 = 0.f;
    for (int r = r0 + h; r < r0 + 256; r += 2){
        float x = X[(size_t)r*HF + c];
        s += x; s2 += x*x;
    }
    __shared__ float l1[256], l2[256];
    l1[threadIdx.x] = s; l2[threadIdx.x] = s2;
    __syncthreads();
    if (threadIdx.x < 128){
        atomicAdd(&stats[c],     l1[threadIdx.x] + l1[threadIdx.x+128]);
        atomicAdd(&stats[128+c], l2[threadIdx.x] + l2[threadIdx.x+128]);
    }
}

// ---------------- BN apply + ReLU + s0 = h @ attW ----------------
__global__ __launch_bounds__(256) void k_bn_s0(float* __restrict__ X, const float* __restrict__ gw,
                                               const float* __restrict__ gb, const float* __restrict__ aw,
                                               const float* __restrict__ stats, float* __restrict__ p0,
                                               float invN){
    int f = threadIdx.x & 127, rl = threadIdx.x >> 7;
    int r = blockIdx.x*2 + rl;
    float mean = stats[f]*invN;
    float var  = stats[128+f]*invN - mean*mean;
    float iv   = rsqrtf(var + 1e-5f);
    float x = X[(size_t)r*HF + f];
    float val = (x - mean)*iv*gw[f] + gb[f];
    val = fmaxf(val, 0.f);
    X[(size_t)r*HF + f] = val;
    __shared__ float red[256];
    red[threadIdx.x] = val * aw[f];
    __syncthreads();
    for (int off = 64; off; off >>= 1){
        if (f < off) red[threadIdx.x] += red[threadIdx.x + off];
        __syncthreads();
    }
    if (f == 0) p0[r] = red[rl << 7];
}

// ---------------- fused Jacobi step: p_new = ca*tin + cc*prev ; out_t = pvec(p_new) ----------------
__global__ __launch_bounds__(256) void k_pvec(const float* __restrict__ tin, const float* __restrict__ prev,
                                              const int* __restrict__ rowptr, const int2* __restrict__ cp,
                                              const float* __restrict__ dinv,
                                              float* __restrict__ outt, float* __restrict__ outp,
                                              float ca, float cc, int Nn){
    int v = blockIdx.x*256 + threadIdx.x;
    if (v >= Nn) return;
    float pv = ca*tin[v] + cc*prev[v];
    outp[v] = pv;
    float dv = dinv[v];
    float acc = 0.f;
    int e1 = rowptr[v+1];
    for (int j = rowptr[v]; j < e1; ++j){
        int2 e = cp[j];
        int s = e.x & (Nn - 1);
        acc += __int_as_float(e.y)*(ca*tin[s] + cc*prev[s]);
    }
    outt[v] = pv*dv*dv + dv*acc;
}
// last Jacobi step + theta combine fused (p3 needs only thread-local t2)
__global__ __launch_bounds__(256) void k_pvec_score(const float* __restrict__ tin,  // t1
                                                    const float* __restrict__ prev, // p0
                                                    const float* __restrict__ p1,
                                                    const int* __restrict__ rowptr, const int2* __restrict__ cp,
                                                    const float* __restrict__ dinv,
                                                    const float* __restrict__ th, float* __restrict__ score,
                                                    float ca2, float cc2, float ca3, float cc3, int Nn){
    int v = blockIdx.x*256 + threadIdx.x;
    if (v >= Nn) return;
    float p2 = ca2*tin[v] + cc2*prev[v];
    float dv = dinv[v];
    float acc = 0.f;
    int e1 = rowptr[v+1];
    for (int j = rowptr[v]; j < e1; ++j){
        int2 e = cp[j];
        int s = e.x & (Nn - 1);
        acc += __int_as_float(e.y)*(ca2*tin[s] + cc2*prev[s]);
    }
    float t2 = p2*dv*dv + dv*acc;
    float p3 = ca3*t2 + cc3*p1[v];
    score[v] = th[0]*prev[v] + th[1]*p1[v] + th[2]*p2 + th[3]*p3;
}

// ---------------- per-graph top-k (bitonic, desc score, ties -> lower idx) ----------------
__global__ __launch_bounds__(256) void k_topk(const float* __restrict__ score, float* __restrict__ ts,
                                              int* __restrict__ newid, int* __restrict__ selmap,
                                              int n, int k){
    __shared__ float ss[512];
    __shared__ int   si[512];
    int g = blockIdx.x, t = threadIdx.x;
    for (int i = t; i < n; i += 256){ ss[i] = score[g*n + i]; si[i] = i; }
    __syncthreads();
    for (int size = 2; size <= n; size <<= 1){
        for (int stride = size >> 1; stride > 0; stride >>= 1){
            for (int i = t; i < n; i += 256){
                int j = i ^ stride;
                if (j > i){
                    bool asc = ((i & size) == 0);
                    float s1 = ss[i], s2 = ss[j];
                    int   i1 = si[i], i2 = si[j];
                    bool gt = (s1 < s2) || (s1 == s2 && i1 > i2);
                    if (gt == asc){ ss[i] = s2; ss[j] = s1; si[i] = i2; si[j] = i1; }
                }
            }
            __syncthreads();
        }
    }
    for (int r = t; r < k; r += 256){
        int old = g*n + si[r];
        int nw  = g*k + r;
        newid[old] = nw;
        selmap[nw] = old;
        ts[nw] = tanhf(ss[r]);
    }
}

// ---------------- gather pooled nodes ----------------
__global__ __launch_bounds__(256) void k_gather(const float* __restrict__ X, const int* __restrict__ selmap,
                                                const float* __restrict__ ts, float* __restrict__ Y, int Nk){
    int gid = blockIdx.x*256 + threadIdx.x;
    int v = gid >> 5, f4 = gid & 31;
    if (v >= Nk) return;
    int o = selmap[v];
    float t = ts[v];
    float4 x = *(const float4*)(X + (size_t)o*HF + f4*4);
    x.x *= t; x.y *= t; x.z *= t; x.w *= t;
    *(float4*)(Y + (size_t)v*HF + f4*4) = x;
}

// ---------------- readout: gacc[g] += [max_j h, mean_j h] ----------------
__global__ __launch_bounds__(256) void k_readout(const float* __restrict__ Y, float* __restrict__ gacc, int k){
    int f = threadIdx.x & 127, h = threadIdx.x >> 7, g = blockIdx.x;
    float mx = -3.4e38f, sm = 0.f;
    for (int j = h; j < k; j += 2){
        float x = Y[((size_t)g*k + j)*HF + f];
        mx = fmaxf(mx, x); sm += x;
    }
    __shared__ float l1[256], l2[256];
    l1[threadIdx.x] = mx; l2[threadIdx.x] = sm;
    __syncthreads();
    if (threadIdx.x < 128){
        mx = fmaxf(l1[f], l1[f+128]);
        sm = l2[f] + l2[f+128];
        gacc[g*256 + f]       += mx;
        gacc[g*256 + 128 + f] += sm / (float)k;
    }
}

// ---------------- edge remap ----------------
__global__ __launch_bounds__(256) void k_remap(int* __restrict__ src, int* __restrict__ dst,
                                               float* __restrict__ w, const int* __restrict__ newid){
    int e = blockIdx.x*256 + threadIdx.x;
    if (e >= ETOT) return;
    if (w[e] > 0.5f){
        int ns = newid[src[e]], nd = newid[dst[e]];
        if (ns >= 0 && nd >= 0){ src[e] = ns; dst[e] = nd; }
        else { src[e] = 0; dst[e] = 0; w[e] = 0.f; }
    } else { src[e] = 0; dst[e] = 0; }
}

// ---------------- head (parallel, fully unrolled) ----------------
__global__ __launch_bounds__(256) void k_head1(const float* __restrict__ gacc, const float* __restrict__ W1,
                                               const float* __restrict__ b1, float* __restrict__ t1,
                                               float* __restrict__ sh){
    int r = blockIdx.x;
    int c = threadIdx.x & 127, h = threadIdx.x >> 7;
    __shared__ float gs[256];
    __shared__ float red[256];
    gs[threadIdx.x] = gacc[r*256 + threadIdx.x];
    __syncthreads();
    float s = 0.f;
    #pragma unroll
    for (int kk = 0; kk < 128; ++kk)
        s += gs[h*128 + kk] * W1[(h*128 + kk)*128 + c];
    red[threadIdx.x] = s;
    __syncthreads();
    if (h == 0){
        float v = (red[c] + red[c+128]) * 0.2f + b1[c];
        t1[r*128 + c] = v;
        atomicAdd(&sh[c], v);
        atomicAdd(&sh[128 + c], v*v);
    }
}
__global__ __launch_bounds__(128) void k_head2(const float* __restrict__ t1, const float* __restrict__ gw,
                                               const float* __restrict__ gb, const float* __restrict__ W2,
                                               const float* __restrict__ b2, float* __restrict__ sh,
                                               float* __restrict__ t2){
    int r = blockIdx.x, t = threadIdx.x;
    int cc = t & 63, h = t >> 6;
    __shared__ float row[128];
    __shared__ float red[128];
    {
        float mean = sh[t] * (1.f/128.f);
        float var  = sh[128+t]*(1.f/128.f) - mean*mean;
        float iv   = rsqrtf(var + 1e-5f);
        float v = (t1[r*128+t] - mean)*iv*gw[t] + gb[t];
        row[t] = fmaxf(v, 0.f);
    }
    __syncthreads();
    float s = 0.f;
    #pragma unroll
    for (int kk = 0; kk < 64; ++kk)
        s += row[h*64+kk] * W2[(h*64+kk)*64 + cc];
    red[t] = s;
    __syncthreads();
    if (h == 0){
        float v = red[cc] + red[cc+64] + b2[cc];
        t2[r*64+cc] = v;
        atomicAdd(&sh[256+cc], v);
        atomicAdd(&sh[320+cc], v*v);
    }
}
__global__ __launch_bounds__(64) void k_head3(const float* __restrict__ t2, const float* __restrict__ gw,
                                              const float* __restrict__ gb, const float* __restrict__ W3,
                                              const float* __restrict__ b3, const float* __restrict__ sh,
                                              float* __restrict__ out){
    int r = blockIdx.x, t = threadIdx.x;  // 64 threads = 1 wave
    float mean = sh[256+t]*(1.f/128.f);
    float var  = sh[320+t]*(1.f/128.f) - mean*mean;
    float iv   = rsqrtf(var + 1e-5f);
    float v = fmaxf((t2[r*64+t]-mean)*iv*gw[t] + gb[t], 0.f);
    float lg[10];
    #pragma unroll
    for (int j = 0; j < 10; ++j){
        float p = v * W3[t*10 + j];
        for (int off = 32; off; off >>= 1) p += __shfl_down(p, off);
        lg[j] = p;
    }
    if (t == 0){
        float m = -3.4e38f;
        #pragma unroll
        for (int j = 0; j < 10; ++j){ lg[j] += b3[j]; m = fmaxf(m, lg[j]); }
        float se = 0.f;
        #pragma unroll
        for (int j = 0; j < 10; ++j) se += expf(lg[j] - m);
        float l = logf(se) + m;
        #pragma unroll
        for (int j = 0; j < 10; ++j) out[r*10 + j] = lg[j] - l;
    }
}

extern "C" void kernel_launch(void* const* d_in, const int* in_sizes, int n_in,
                              void* d_out, int out_size, void* d_ws, size_t ws_size,
                              hipStream_t stream){
    const float* x     = (const float*)d_in[0];
    const float* convW = (const float*)d_in[1];
    const float* convb = (const float*)d_in[2];
    const float* bnW   = (const float*)d_in[3];
    const float* bnB   = (const float*)d_in[4];
    const float* bn7W  = (const float*)d_in[5];
    const float* bn7B  = (const float*)d_in[6];
    const float* attW  = (const float*)d_in[7];
    const float* theta = (const float*)d_in[8];
    const float* lin1W = (const float*)d_in[9];
    const float* lin1b = (const float*)d_in[10];
    const float* lin2W = (const float*)d_in[11];
    const float* lin2b = (const float*)d_in[12];
    const float* lin3W = (const float*)d_in[13];
    const float* lin3b = (const float*)d_in[14];

    char* base = (char*)d_ws;
    size_t off = 0;
    auto take = [&](size_t bytes) -> void* {
        void* p = base + off;
        off = (off + bytes + 255) & ~(size_t)255;
        return p;
    };
    float* bufA  = (float*)take((size_t)N0G*HF*4);
    float* bufB  = (float*)take((size_t)N0G*HF*4);
    float* w     = (float*)take((size_t)ETOT*4);
    int*   srcw  = (int*)  take((size_t)ETOT*4);
    int*   dstw  = (int*)  take((size_t)ETOT*4);
    int*   cnt   = (int*)  take((size_t)N0G*4);
    int*   rowp  = (int*)  take((size_t)(N0G+1)*4);
    int*   curs  = (int*)  take((size_t)N0G*4);
    float* dinv  = (float*)take((size_t)N0G*4);
    int2*  csr_p = (int2*) take((size_t)ETOT*8);
    int*   psum  = (int*)  take(256*4);
    int*   boff  = (int*)  take(256*4);
    float* p0v   = (float*)take((size_t)N0G*4);
    float* p1v   = (float*)take((size_t)N0G*4);
    float* tAv   = (float*)take((size_t)N0G*4);
    float* tBv   = (float*)take((size_t)N0G*4);
    float* scv   = (float*)take((size_t)N0G*4);
    float* tsv   = (float*)take((size_t)(N0G/2)*4);
    int*   newid = (int*)  take((size_t)N0G*4);
    int*   selmap= (int*)  take((size_t)(N0G/2)*4);
    float* stats = (float*)take(256*4);
    float* gacc  = (float*)take((size_t)B_GRAPH*256*4);
    float* t1    = (float*)take((size_t)B_GRAPH*128*4);
    float* t2    = (float*)take((size_t)B_GRAPH*64*4);
    float* statsH= (float*)take(384*4);

    // Jacobi coefficients (A=B=1 -> c2 term is 0)
    auto coef = [](int kk, float& ca, float& cc){
        double a = 1.0, b = 1.0;
        double c0 = 2.0*kk*(kk+a+b)*(2.0*kk+a+b-2.0);
        double c1 = (2.0*kk+a+b-1.0)*(2.0*kk+a+b)*(2.0*kk+a+b-2.0);
        double c3 = 2.0*(kk+a-1.0)*(kk+b-1.0)*(2.0*kk+a+b);
        ca = (float)(c1/c0); cc = (float)(-c3/c0);
    };
    float ca2, cc2, ca3, cc3;
    coef(2, ca2, cc2);
    coef(3, ca3, cc3);

    hipMemcpyAsync(srcw, d_in[15], (size_t)ETOT*4, hipMemcpyDeviceToDevice, stream);
    hipMemcpyAsync(dstw, d_in[16], (size_t)ETOT*4, hipMemcpyDeviceToDevice, stream);
    k_fill1<<<ETOT/256, 256, 0, stream>>>(w, ETOT);
    hipMemsetAsync(gacc, 0, (size_t)B_GRAPH*256*4, stream);

    for (int i = 0; i < 5; ++i){
        int n = 512 >> i, k = n >> 1;
        int Nn = B_GRAPH*n, Nk = B_GRAPH*k;
        int nb = Nn/256;
        int lb = 6 - i;                    // log2(blocks per graph) for k_prop: n/8 = 2^lb
        float* hin = (i & 1) ? bufB : bufA;
        float* tmp = (i & 1) ? bufA : bufB;
        const float* gemmA = (i == 0) ? x : hin;   // level 0 reads x directly

        hipMemsetAsync(cnt, 0, (size_t)Nn*4, stream);
        k_hist<<<ETOT/256, 256, 0, stream>>>(dstw, w, cnt);
        k_part<<<nb, 256, 0, stream>>>(cnt, psum);
        k_mid<<<1, 256, 0, stream>>>(psum, boff, rowp, nb, Nn);
        k_final<<<nb, 256, 0, stream>>>(cnt, boff, rowp, dinv, curs);
        k_scatter<<<ETOT/256, 256, 0, stream>>>(srcw, dstw, w, dinv, curs, csr_p);

        k_gemm<<<Nn/64, 256, 0, stream>>>(gemmA, convW + (size_t)i*HF*HF, tmp);
        k_prop<<<(Nn*32)/256, 256, 0, stream>>>(tmp, convb + i*HF, rowp, csr_p, dinv, hin, n, lb, Nn);

        hipMemsetAsync(stats, 0, 256*4, stream);
        k_bnstats<<<Nn/256, 256, 0, stream>>>(hin, stats);
        k_bn_s0<<<Nn/2, 256, 0, stream>>>(hin, bnW + i*HF, bnB + i*HF, attW + i*HF, stats, p0v, 1.0f/(float)Nn);

        // Jacobi: t0=pvec(p0); p1=2*t0, t1=pvec(p1); fused: p2=ca2*t1+cc2*p0, t2=pvec(p2), p3, score
        k_pvec<<<Nn/256, 256, 0, stream>>>(p0v, p0v, rowp, csr_p, dinv, tAv, scv, 1.0f, 0.0f, Nn);
        k_pvec<<<Nn/256, 256, 0, stream>>>(tAv, p0v, rowp, csr_p, dinv, tBv, p1v, 2.0f, 0.0f, Nn);
        k_pvec_score<<<Nn/256, 256, 0, stream>>>(tBv, p0v, p1v, rowp, csr_p, dinv, theta + i*4, scv,
                                                 ca2, cc2, ca3, cc3, Nn);

        hipMemsetAsync(newid, 0xFF, (size_t)Nn*4, stream);   // -1
        k_topk<<<B_GRAPH, 256, 0, stream>>>(scv, tsv, newid, selmap, n, k);
        k_gather<<<(Nk*32)/256, 256, 0, stream>>>(hin, selmap, tsv, tmp, Nk);
        k_readout<<<B_GRAPH, 256, 0, stream>>>(tmp, gacc, k);
        k_remap<<<ETOT/256, 256, 0, stream>>>(srcw, dstw, w, newid);
    }

    hipMemsetAsync(statsH, 0, 384*4, stream);
    k_head1<<<B_GRAPH, 256, 0, stream>>>(gacc, lin1W, lin1b, t1, statsH);
    k_head2<<<B_GRAPH, 128, 0, stream>>>(t1, bnW + 5*HF, bnB + 5*HF, lin2W, lin2b, statsH, t2);
    k_head3<<<B_GRAPH, 64, 0, stream>>>(t2, bn7W, bn7B, lin3W, lin3b, statsH, (float*)d_out);
}

// Round 6
// 744.528 us; speedup vs baseline: 1.5528x; 1.1427x over previous
//
#include <hip/hip_runtime.h>
#include <hip/hip_bf16.h>

#define B_GRAPH 128
#define ETOT    (128*4096)   // 524288 edges (static)
#define N0G     (128*512)    // 65536 nodes at level 0
#define HF      128

// ---------------- level-0 init: copy edges, w=1, per-graph CSR build, zero gacc/statsH ----------------
__global__ __launch_bounds__(256) void k_init(const int* __restrict__ s_in, const int* __restrict__ d_in_,
                                              int* __restrict__ srcw, int* __restrict__ dstw,
                                              float* __restrict__ wv, int2* __restrict__ csr,
                                              int2* __restrict__ rb2, float* __restrict__ dinvv,
                                              float* __restrict__ gacc, float* __restrict__ statsH){
    int g = blockIdx.x, t = threadIdx.x;
    __shared__ int cnt[512];
    __shared__ int cur[512];
    __shared__ float dvl[512];
    for (int l = t; l < 512; l += 256) cnt[l] = 0;
    gacc[g*256 + t] = 0.f;
    if (g == 0){ if (t < 256){ statsH[t] = 0.f; if (t < 128) statsH[256+t] = 0.f; } }
    __syncthreads();
    for (int j = t; j < 4096; j += 256){
        int e = g*4096 + j;
        int sg = s_in[e], dg = d_in_[e];
        srcw[e] = sg; dstw[e] = dg; wv[e] = 1.f;
        atomicAdd(&cnt[dg & 511], 1);
    }
    __syncthreads();
    // exclusive scan of cnt[512] with 256 threads (pairwise + Hillis-Steele)
    int c0 = cnt[2*t], c1 = cnt[2*t+1];
    int pairsum = c0 + c1;
    cur[t] = pairsum;
    __syncthreads();
    for (int off = 1; off < 256; off <<= 1){
        int a = (t >= off) ? cur[t-off] : 0;
        __syncthreads();
        cur[t] += a;
        __syncthreads();
    }
    int begpair = cur[t] - pairsum;
    __syncthreads();
    cur[2*t]   = begpair;
    cur[2*t+1] = begpair + c0;
    __syncthreads();
    for (int l = t; l < 512; l += 256){
        rb2[g*512 + l] = make_int2(g*4096 + cur[l], cnt[l]);
        float dv = rsqrtf((float)cnt[l] + 1.f);
        dvl[l] = dv;
        dinvv[g*512 + l] = dv;
    }
    __syncthreads();
    for (int j = t; j < 4096; j += 256){
        int e = g*4096 + j;
        int sg = srcw[e], dl = dstw[e] & 511;
        int p = atomicAdd(&cur[dl], 1);
        csr[g*4096 + p] = make_int2(sg, __float_as_int(dvl[sg & 511]));
    }
}

// ---------------- GEMM: C[N,128] = A[N,128] @ W[128,128]; 32KB W-halves; block0 zeroes stats ----------------
__global__ __launch_bounds__(256) void k_gemm(const float* __restrict__ A, const float* __restrict__ Wg,
                                              float* __restrict__ C, float* __restrict__ stats){
    __shared__ float Ws[64*HF];
    if (blockIdx.x == 0) stats[threadIdx.x] = 0.f;    // zeroed before bnstats dispatch
    int tx = threadIdx.x & 15, ty = threadIdx.x >> 4;
    int r0 = blockIdx.x*64 + ty*4, c0 = tx*4;
    float acc[4][8];
    #pragma unroll
    for (int j=0;j<4;++j)
        #pragma unroll
        for (int l=0;l<8;++l) acc[j][l] = 0.f;
    for (int kh = 0; kh < 2; ++kh){
        __syncthreads();
        {
            float4* d4 = (float4*)Ws;
            const float4* s4 = (const float4*)(Wg + kh*64*HF);
            for (int i = threadIdx.x; i < 64*HF/4; i += 256) d4[i] = s4[i];
        }
        __syncthreads();
        for (int k4 = 0; k4 < 16; ++k4){
            float4 av[4];
            #pragma unroll
            for (int j=0;j<4;++j)
                av[j] = *(const float4*)(A + (size_t)(r0+j)*HF + kh*64 + k4*4);
            #pragma unroll
            for (int kk=0; kk<4; ++kk){
                int kl = k4*4 + kk;
                float4 w0 = *(const float4*)(Ws + kl*HF + c0);
                float4 w1 = *(const float4*)(Ws + kl*HF + c0 + 64);
                #pragma unroll
                for (int j=0;j<4;++j){
                    float a = reinterpret_cast<const float*>(&av[j])[kk];
                    acc[j][0] += a*w0.x; acc[j][1] += a*w0.y; acc[j][2] += a*w0.z; acc[j][3] += a*w0.w;
                    acc[j][4] += a*w1.x; acc[j][5] += a*w1.y; acc[j][6] += a*w1.z; acc[j][7] += a*w1.w;
                }
            }
        }
    }
    #pragma unroll
    for (int j=0;j<4;++j){
        *(float4*)(C + (size_t)(r0+j)*HF + c0)      = make_float4(acc[j][0],acc[j][1],acc[j][2],acc[j][3]);
        *(float4*)(C + (size_t)(r0+j)*HF + c0 + 64) = make_float4(acc[j][4],acc[j][5],acc[j][6],acc[j][7]);
    }
}

// ---------------- prop: X[v] = Y[v]*dv*dv + dv * sum_e dinv[s]*Y[s] + convb (XCD swizzle) ----------------
__global__ __launch_bounds__(256) void k_prop(const float* __restrict__ Y, const float* __restrict__ cb,
                                              const int2* __restrict__ rb2, const int2* __restrict__ cp,
                                              const float* __restrict__ dinv,
                                              float* __restrict__ X, int n, int lb, int Nn){
    int xcd = blockIdx.x & 7, c = blockIdx.x >> 3;
    int g = xcd*16 + (c >> lb);
    int m = c & ((1 << lb) - 1);
    int v = g*n + m*8 + (threadIdx.x >> 5);
    int f4 = threadIdx.x & 31;
    float dv = dinv[v];
    float4 y = *(const float4*)(Y + (size_t)v*HF + f4*4);
    float4 acc = make_float4(0.f, 0.f, 0.f, 0.f);
    int2 rb = rb2[v];
    int e0 = rb.x, e1 = rb.x + rb.y;
    for (int j = e0; j < e1; ++j){
        int2 e = cp[j];
        int s = e.x & (Nn - 1);
        float en = __int_as_float(e.y);
        float4 h = *(const float4*)(Y + (size_t)s*HF + f4*4);
        acc.x += en*h.x; acc.y += en*h.y; acc.z += en*h.z; acc.w += en*h.w;
    }
    int f = f4*4;
    acc.x = y.x*dv*dv + dv*acc.x + cb[f];
    acc.y = y.y*dv*dv + dv*acc.y + cb[f+1];
    acc.z = y.z*dv*dv + dv*acc.z + cb[f+2];
    acc.w = y.w*dv*dv + dv*acc.w + cb[f+3];
    *(float4*)(X + (size_t)v*HF + f) = acc;
}

// ---------------- BN stats (sum, sumsq per column) ----------------
__global__ __launch_bounds__(256) void k_bnstats(const float* __restrict__ X, float* __restrict__ stats){
    int c = threadIdx.x & 127, h = threadIdx.x >> 7;
    int r0 = blockIdx.x * 256;
    float s = 0.f, s2 = 0.f;
    for (int r = r0 + h; r < r0 + 256; r += 2){
        float x = X[(size_t)r*HF + c];
        s += x; s2 += x*x;
    }
    __shared__ float l1[256], l2[256];
    l1[threadIdx.x] = s; l2[threadIdx.x] = s2;
    __syncthreads();
    if (threadIdx.x < 128){
        atomicAdd(&stats[c],     l1[threadIdx.x] + l1[threadIdx.x+128]);
        atomicAdd(&stats[128+c], l2[threadIdx.x] + l2[threadIdx.x+128]);
    }
}

// ---------------- mega-fused per-graph kernel ----------------
// BN+ReLU+s0 -> Jacobi pvec x3 -> score -> topk -> gather(+BN)+readout -> remap -> next-level CSR
__global__ __launch_bounds__(256) void k_graph(
    const float* __restrict__ H, const float* __restrict__ stats,
    const float* __restrict__ gw, const float* __restrict__ gb,
    const float* __restrict__ aw, const float* __restrict__ th,
    const int2* __restrict__ rb2, int2* __restrict__ csr, const float* __restrict__ dinv,
    int* __restrict__ srcw, int* __restrict__ dstw, float* __restrict__ wv,
    float* __restrict__ P, float* __restrict__ gacc,
    int2* __restrict__ rb2n, float* __restrict__ dinvn,
    float invN, float ca2, float cc2, float ca3, float cc3,
    int n, int last)
{
    int g = blockIdx.x, t = threadIdx.x;
    int k = n >> 1;
    __shared__ int2  eds[4096];
    __shared__ int2  rbl[512];
    __shared__ float dvv[512], p0[512], p1[512], p2[512];
    __shared__ float ss[512];
    __shared__ int   si[512];
    __shared__ float tss[256];
    __shared__ int   nid[512];
    __shared__ int   cntN[256], curN[256];
    __shared__ float dvn[256];
    __shared__ float bna[128], bnb[128];
    __shared__ float red[256];

    if (t < 128){
        float mean = stats[t]*invN;
        float var  = stats[128+t]*invN - mean*mean;
        float iv   = rsqrtf(var + 1e-5f);
        bna[t] = iv*gw[t];
        bnb[t] = gb[t] - mean*iv*gw[t];
    }
    for (int l = t; l < n; l += 256){
        int2 rb = rb2[g*n + l];
        rbl[l] = make_int2(rb.x - g*4096, rb.y);
        dvv[l] = dinv[g*n + l];
    }
    __syncthreads();
    int medg = rbl[n-1].x + rbl[n-1].y;
    for (int j = t; j < medg; j += 256){
        int2 e = csr[g*4096 + j];
        eds[j] = make_int2(e.x & (n-1), e.y);   // local src, dinv bits
    }
    // s0 per node: one wave per node, shuffle reduce (no extra barriers)
    int lane = t & 63, wid = t >> 6;
    for (int l = wid; l < n; l += 4){
        const float* hp = H + ((size_t)g*n + l)*HF;
        float a0 = hp[lane], a1 = hp[lane+64];
        float v0 = fmaxf(a0*bna[lane]    + bnb[lane],    0.f) * aw[lane];
        float v1 = fmaxf(a1*bna[lane+64] + bnb[lane+64], 0.f) * aw[lane+64];
        float p = v0 + v1;
        for (int off = 32; off; off >>= 1) p += __shfl_down(p, off);
        if (lane == 0) p0[l] = p;
    }
    __syncthreads();
    // pvec 1: p1 = 2 * pvec(p0)
    for (int l = t; l < n; l += 256){
        int2 rc = rbl[l];
        float acc = 0.f;
        for (int j = 0; j < rc.y; ++j){
            int2 e = eds[rc.x + j];
            acc += __int_as_float(e.y) * p0[e.x];
        }
        float dv = dvv[l];
        p1[l] = 2.f*(p0[l]*dv*dv + dv*acc);
    }
    __syncthreads();
    // pvec 2: p2 = ca2*pvec(p1) + cc2*p0
    for (int l = t; l < n; l += 256){
        int2 rc = rbl[l];
        float acc = 0.f;
        for (int j = 0; j < rc.y; ++j){
            int2 e = eds[rc.x + j];
            acc += __int_as_float(e.y) * p1[e.x];
        }
        float dv = dvv[l];
        p2[l] = ca2*(p1[l]*dv*dv + dv*acc) + cc2*p0[l];
    }
    __syncthreads();
    // pvec 3 + theta combine -> score
    float t0v = th[0], t1v = th[1], t2c = th[2], t3v = th[3];
    for (int l = t; l < n; l += 256){
        int2 rc = rbl[l];
        float acc = 0.f;
        for (int j = 0; j < rc.y; ++j){
            int2 e = eds[rc.x + j];
            acc += __int_as_float(e.y) * p2[e.x];
        }
        float dv = dvv[l];
        float tv = p2[l]*dv*dv + dv*acc;
        float p3 = ca3*tv + cc3*p1[l];
        ss[l] = t0v*p0[l] + t1v*p1[l] + t2c*p2[l] + t3v*p3;
        si[l] = l;
    }
    __syncthreads();
    // bitonic sort desc by (score, -idx)
    for (int size = 2; size <= n; size <<= 1){
        for (int stride = size >> 1; stride > 0; stride >>= 1){
            for (int i = t; i < n; i += 256){
                int j = i ^ stride;
                if (j > i){
                    bool asc = ((i & size) == 0);
                    float s1 = ss[i], s2 = ss[j];
                    int   i1 = si[i], i2 = si[j];
                    bool gt = (s1 < s2) || (s1 == s2 && i1 > i2);
                    if (gt == asc){ ss[i] = s2; ss[j] = s1; si[i] = i2; si[j] = i1; }
                }
            }
            __syncthreads();
        }
    }
    for (int l = t; l < n; l += 256) nid[l] = -1;
    __syncthreads();
    for (int r = t; r < k; r += 256){
        nid[si[r]] = r;
        tss[r] = tanhf(ss[r]);
    }
    __syncthreads();
    // gather (BN+ReLU on the fly, scale by tanh) + readout max/mean
    {
        int f = t & 127, rl = t >> 7;
        float af = bna[f], bf = bnb[f];
        float mx = -3.4e38f, sm = 0.f;
        for (int r = rl; r < k; r += 2){
            int old = si[r];
            float hv = H[((size_t)g*n + old)*HF + f];
            float v = fmaxf(hv*af + bf, 0.f) * tss[r];
            P[((size_t)g*k + r)*HF + f] = v;
            mx = fmaxf(mx, v); sm += v;
        }
        red[t] = mx;
        __syncthreads();
        if (t < 128) gacc[g*256 + f] += fmaxf(red[f], red[f+128]);
        __syncthreads();
        red[t] = sm;
        __syncthreads();
        if (t < 128) gacc[g*256 + 128 + f] += (red[f] + red[f+128]) / (float)k;
    }
    if (last) return;
    __syncthreads();
    // remap edges + next-level CSR build (all block-local)
    if (t < k) cntN[t] = 0;
    __syncthreads();
    for (int j = t; j < 4096; j += 256){
        int e = g*4096 + j;
        float we = wv[e];
        int valid = 0, ns = 0, nd = 0;
        if (we > 0.5f){
            int sl = srcw[e] & (n-1);
            int dl = dstw[e] & (n-1);
            ns = nid[sl]; nd = nid[dl];
            valid = (ns >= 0) && (nd >= 0);
        }
        if (valid){
            srcw[e] = g*k + ns; dstw[e] = g*k + nd; wv[e] = 1.f;
            atomicAdd(&cntN[nd], 1);
        } else {
            srcw[e] = 0; dstw[e] = 0; wv[e] = 0.f;
        }
    }
    __syncthreads();
    // scan cntN (k <= 256) via si as temp
    int c = (t < k) ? cntN[t] : 0;
    si[t] = c;
    __syncthreads();
    for (int off = 1; off < 256; off <<= 1){
        int a = (t >= off) ? si[t-off] : 0;
        __syncthreads();
        si[t] += a;
        __syncthreads();
    }
    int beg = si[t] - c;
    if (t < k){
        rb2n[g*k + t] = make_int2(g*4096 + beg, c);
        float dv = rsqrtf((float)c + 1.f);
        dinvn[g*k + t] = dv;
        dvn[t] = dv;
        curN[t] = beg;
    }
    __syncthreads();
    for (int j = t; j < 4096; j += 256){
        int e = g*4096 + j;
        if (wv[e] > 0.5f){
            int sg = srcw[e], dl = dstw[e] & (k-1);
            int p = atomicAdd(&curN[dl], 1);
            csr[g*4096 + p] = make_int2(sg, __float_as_int(dvn[sg & (k-1)]));
        }
    }
}

// ---------------- head (parallel, fully unrolled) ----------------
__global__ __launch_bounds__(256) void k_head1(const float* __restrict__ gacc, const float* __restrict__ W1,
                                               const float* __restrict__ b1, float* __restrict__ t1,
                                               float* __restrict__ sh){
    int r = blockIdx.x;
    int c = threadIdx.x & 127, h = threadIdx.x >> 7;
    __shared__ float gs[256];
    __shared__ float red[256];
    gs[threadIdx.x] = gacc[r*256 + threadIdx.x];
    __syncthreads();
    float s = 0.f;
    #pragma unroll
    for (int kk = 0; kk < 128; ++kk)
        s += gs[h*128 + kk] * W1[(h*128 + kk)*128 + c];
    red[threadIdx.x] = s;
    __syncthreads();
    if (h == 0){
        float v = (red[c] + red[c+128]) * 0.2f + b1[c];
        t1[r*128 + c] = v;
        atomicAdd(&sh[c], v);
        atomicAdd(&sh[128 + c], v*v);
    }
}
__global__ __launch_bounds__(128) void k_head2(const float* __restrict__ t1, const float* __restrict__ gw,
                                               const float* __restrict__ gb, const float* __restrict__ W2,
                                               const float* __restrict__ b2, float* __restrict__ sh,
                                               float* __restrict__ t2){
    int r = blockIdx.x, t = threadIdx.x;
    int cc = t & 63, h = t >> 6;
    __shared__ float row[128];
    __shared__ float red[128];
    {
        float mean = sh[t] * (1.f/128.f);
        float var  = sh[128+t]*(1.f/128.f) - mean*mean;
        float iv   = rsqrtf(var + 1e-5f);
        float v = (t1[r*128+t] - mean)*iv*gw[t] + gb[t];
        row[t] = fmaxf(v, 0.f);
    }
    __syncthreads();
    float s = 0.f;
    #pragma unroll
    for (int kk = 0; kk < 64; ++kk)
        s += row[h*64+kk] * W2[(h*64+kk)*64 + cc];
    red[t] = s;
    __syncthreads();
    if (h == 0){
        float v = red[cc] + red[cc+64] + b2[cc];
        t2[r*64+cc] = v;
        atomicAdd(&sh[256+cc], v);
        atomicAdd(&sh[320+cc], v*v);
    }
}
__global__ __launch_bounds__(64) void k_head3(const float* __restrict__ t2, const float* __restrict__ gw,
                                              const float* __restrict__ gb, const float* __restrict__ W3,
                                              const float* __restrict__ b3, const float* __restrict__ sh,
                                              float* __restrict__ out){
    int r = blockIdx.x, t = threadIdx.x;
    float mean = sh[256+t]*(1.f/128.f);
    float var  = sh[320+t]*(1.f/128.f) - mean*mean;
    float iv   = rsqrtf(var + 1e-5f);
    float v = fmaxf((t2[r*64+t]-mean)*iv*gw[t] + gb[t], 0.f);
    float lg[10];
    #pragma unroll
    for (int j = 0; j < 10; ++j){
        float p = v * W3[t*10 + j];
        for (int off = 32; off; off >>= 1) p += __shfl_down(p, off);
        lg[j] = p;
    }
    if (t == 0){
        float m = -3.4e38f;
        #pragma unroll
        for (int j = 0; j < 10; ++j){ lg[j] += b3[j]; m = fmaxf(m, lg[j]); }
        float se = 0.f;
        #pragma unroll
        for (int j = 0; j < 10; ++j) se += expf(lg[j] - m);
        float l = logf(se) + m;
        #pragma unroll
        for (int j = 0; j < 10; ++j) out[r*10 + j] = lg[j] - l;
    }
}

extern "C" void kernel_launch(void* const* d_in, const int* in_sizes, int n_in,
                              void* d_out, int out_size, void* d_ws, size_t ws_size,
                              hipStream_t stream){
    const float* x     = (const float*)d_in[0];
    const float* convW = (const float*)d_in[1];
    const float* convb = (const float*)d_in[2];
    const float* bnW   = (const float*)d_in[3];
    const float* bnB   = (const float*)d_in[4];
    const float* bn7W  = (const float*)d_in[5];
    const float* bn7B  = (const float*)d_in[6];
    const float* attW  = (const float*)d_in[7];
    const float* theta = (const float*)d_in[8];
    const float* lin1W = (const float*)d_in[9];
    const float* lin1b = (const float*)d_in[10];
    const float* lin2W = (const float*)d_in[11];
    const float* lin2b = (const float*)d_in[12];
    const float* lin3W = (const float*)d_in[13];
    const float* lin3b = (const float*)d_in[14];
    const int*   src0  = (const int*)d_in[15];
    const int*   dst0  = (const int*)d_in[16];

    char* base = (char*)d_ws;
    size_t off = 0;
    auto take = [&](size_t bytes) -> void* {
        void* p = base + off;
        off = (off + bytes + 255) & ~(size_t)255;
        return p;
    };
    // bufGP: level-0 G uses full 32MB; later levels: G at +16MB floats, P at base (disjoint)
    float* bufGP = (float*)take((size_t)N0G*HF*4);
    float* bufH  = (float*)take((size_t)N0G*HF*4);
    int*   srcw  = (int*)  take((size_t)ETOT*4);
    int*   dstw  = (int*)  take((size_t)ETOT*4);
    float* w     = (float*)take((size_t)ETOT*4);
    int2*  csr_p = (int2*) take((size_t)ETOT*8);
    int2*  rb2A  = (int2*) take((size_t)N0G*8);
    int2*  rb2B  = (int2*) take((size_t)N0G*8);
    float* dinvA = (float*)take((size_t)N0G*4);
    float* dinvB = (float*)take((size_t)N0G*4);
    float* stats = (float*)take(256*4);
    float* gacc  = (float*)take((size_t)B_GRAPH*256*4);
    float* t1    = (float*)take((size_t)B_GRAPH*128*4);
    float* t2    = (float*)take((size_t)B_GRAPH*64*4);
    float* statsH= (float*)take(384*4);

    auto coef = [](int kk, float& ca, float& cc){
        double a = 1.0, b = 1.0;
        double c0 = 2.0*kk*(kk+a+b)*(2.0*kk+a+b-2.0);
        double c1 = (2.0*kk+a+b-1.0)*(2.0*kk+a+b)*(2.0*kk+a+b-2.0);
        double c3 = 2.0*(kk+a-1.0)*(kk+b-1.0)*(2.0*kk+a+b);
        ca = (float)(c1/c0); cc = (float)(-c3/c0);
    };
    float ca2, cc2, ca3, cc3;
    coef(2, ca2, cc2);
    coef(3, ca3, cc3);

    k_init<<<B_GRAPH, 256, 0, stream>>>(src0, dst0, srcw, dstw, w, csr_p, rb2A, dinvA, gacc, statsH);

    for (int i = 0; i < 5; ++i){
        int n = 512 >> i;
        int Nn = B_GRAPH*n;
        int lb = 6 - i;
        int2*  rb_cur = (i & 1) ? rb2B : rb2A;
        int2*  rb_nxt = (i & 1) ? rb2A : rb2B;
        float* dv_cur = (i & 1) ? dinvB : dinvA;
        float* dv_nxt = (i & 1) ? dinvA : dinvB;
        const float* gemmA = (i == 0) ? x : bufGP;              // pooled P lives at bufGP base
        float* G = (i == 0) ? bufGP : (bufGP + (size_t)4*1024*1024);  // +16MB floats

        k_gemm<<<Nn/64, 256, 0, stream>>>(gemmA, convW + (size_t)i*HF*HF, G, stats);
        k_prop<<<Nn/8, 256, 0, stream>>>(G, convb + i*HF, rb_cur, csr_p, dv_cur, bufH, n, lb, Nn);
        k_bnstats<<<Nn/256, 256, 0, stream>>>(bufH, stats);
        k_graph<<<B_GRAPH, 256, 0, stream>>>(bufH, stats, bnW + i*HF, bnB + i*HF, attW + i*HF,
                                             theta + i*4, rb_cur, csr_p, dv_cur,
                                             srcw, dstw, w, bufGP, gacc, rb_nxt, dv_nxt,
                                             1.0f/(float)Nn, ca2, cc2, ca3, cc3, n, (i == 4) ? 1 : 0);
    }

    k_head1<<<B_GRAPH, 256, 0, stream>>>(gacc, lin1W, lin1b, t1, statsH);
    k_head2<<<B_GRAPH, 128, 0, stream>>>(t1, bnW + 5*HF, bnB + 5*HF, lin2W, lin2b, statsH, t2);
    k_head3<<<B_GRAPH, 64, 0, stream>>>(t2, bn7W, bn7B, lin3W, lin3b, statsH, (float*)d_out);
}

// Round 7
// 584.854 us; speedup vs baseline: 1.9768x; 1.2730x over previous
//
#include <hip/hip_runtime.h>
#include <hip/hip_bf16.h>

#define B_GRAPH 128
#define ETOT    (128*4096)   // 524288 edges (static)
#define N0G     (128*512)    // 65536 nodes at level 0
#define HF      128

// ---------------- level-0 init: copy edges, w=1, per-graph CSR build, zero gacc/statsH ----------------
__global__ __launch_bounds__(256) void k_init(const int* __restrict__ s_in, const int* __restrict__ d_in_,
                                              int* __restrict__ srcw, int* __restrict__ dstw,
                                              float* __restrict__ wv, int2* __restrict__ csr,
                                              int2* __restrict__ rb2, float* __restrict__ dinvv,
                                              float* __restrict__ gacc, float* __restrict__ statsH){
    int g = blockIdx.x, t = threadIdx.x;
    __shared__ int cnt[512];
    __shared__ int cur[512];
    __shared__ float dvl[512];
    for (int l = t; l < 512; l += 256) cnt[l] = 0;
    gacc[g*256 + t] = 0.f;
    if (g == 0){ if (t < 256){ statsH[t] = 0.f; if (t < 128) statsH[256+t] = 0.f; } }
    __syncthreads();
    for (int j = t; j < 4096; j += 256){
        int e = g*4096 + j;
        int sg = s_in[e], dg = d_in_[e];
        srcw[e] = sg; dstw[e] = dg; wv[e] = 1.f;
        atomicAdd(&cnt[dg & 511], 1);
    }
    __syncthreads();
    // exclusive scan of cnt[512] with 256 threads (pairwise + Hillis-Steele)
    int c0 = cnt[2*t], c1 = cnt[2*t+1];
    int pairsum = c0 + c1;
    cur[t] = pairsum;
    __syncthreads();
    for (int off = 1; off < 256; off <<= 1){
        int a = (t >= off) ? cur[t-off] : 0;
        __syncthreads();
        cur[t] += a;
        __syncthreads();
    }
    int begpair = cur[t] - pairsum;
    __syncthreads();
    cur[2*t]   = begpair;
    cur[2*t+1] = begpair + c0;
    __syncthreads();
    for (int l = t; l < 512; l += 256){
        rb2[g*512 + l] = make_int2(g*4096 + cur[l], cnt[l]);
        float dv = rsqrtf((float)cnt[l] + 1.f);
        dvl[l] = dv;
        dinvv[g*512 + l] = dv;
    }
    __syncthreads();
    for (int j = t; j < 4096; j += 256){
        int e = g*4096 + j;
        int sg = srcw[e], dl = dstw[e] & 511;
        int p = atomicAdd(&cur[dl], 1);
        csr[g*4096 + p] = make_int2(sg, __float_as_int(dvl[sg & 511]));
    }
}

// ---------------- GEMM: C[N,128] = A[N,128] @ W[128,128]; 32KB W-halves; block0 zeroes stats ----------------
__global__ __launch_bounds__(256) void k_gemm(const float* __restrict__ A, const float* __restrict__ Wg,
                                              float* __restrict__ C, float* __restrict__ stats){
    __shared__ float Ws[64*HF];
    if (blockIdx.x == 0) stats[threadIdx.x] = 0.f;    // zeroed before bnstats dispatch
    int tx = threadIdx.x & 15, ty = threadIdx.x >> 4;
    int r0 = blockIdx.x*64 + ty*4, c0 = tx*4;
    float acc[4][8];
    #pragma unroll
    for (int j=0;j<4;++j)
        #pragma unroll
        for (int l=0;l<8;++l) acc[j][l] = 0.f;
    for (int kh = 0; kh < 2; ++kh){
        __syncthreads();
        {
            float4* d4 = (float4*)Ws;
            const float4* s4 = (const float4*)(Wg + kh*64*HF);
            for (int i = threadIdx.x; i < 64*HF/4; i += 256) d4[i] = s4[i];
        }
        __syncthreads();
        for (int k4 = 0; k4 < 16; ++k4){
            float4 av[4];
            #pragma unroll
            for (int j=0;j<4;++j)
                av[j] = *(const float4*)(A + (size_t)(r0+j)*HF + kh*64 + k4*4);
            #pragma unroll
            for (int kk=0; kk<4; ++kk){
                int kl = k4*4 + kk;
                float4 w0 = *(const float4*)(Ws + kl*HF + c0);
                float4 w1 = *(const float4*)(Ws + kl*HF + c0 + 64);
                #pragma unroll
                for (int j=0;j<4;++j){
                    float a = reinterpret_cast<const float*>(&av[j])[kk];
                    acc[j][0] += a*w0.x; acc[j][1] += a*w0.y; acc[j][2] += a*w0.z; acc[j][3] += a*w0.w;
                    acc[j][4] += a*w1.x; acc[j][5] += a*w1.y; acc[j][6] += a*w1.z; acc[j][7] += a*w1.w;
                }
            }
        }
    }
    #pragma unroll
    for (int j=0;j<4;++j){
        *(float4*)(C + (size_t)(r0+j)*HF + c0)      = make_float4(acc[j][0],acc[j][1],acc[j][2],acc[j][3]);
        *(float4*)(C + (size_t)(r0+j)*HF + c0 + 64) = make_float4(acc[j][4],acc[j][5],acc[j][6],acc[j][7]);
    }
}

// ---------------- prop: X[v] = Y[v]*dv*dv + dv * sum_e dinv[s]*Y[s] + convb (XCD swizzle) ----------------
__global__ __launch_bounds__(256) void k_prop(const float* __restrict__ Y, const float* __restrict__ cb,
                                              const int2* __restrict__ rb2, const int2* __restrict__ cp,
                                              const float* __restrict__ dinv,
                                              float* __restrict__ X, int n, int lb, int Nn){
    int xcd = blockIdx.x & 7, c = blockIdx.x >> 3;
    int g = xcd*16 + (c >> lb);
    int m = c & ((1 << lb) - 1);
    int v = g*n + m*8 + (threadIdx.x >> 5);
    int f4 = threadIdx.x & 31;
    float dv = dinv[v];
    float4 y = *(const float4*)(Y + (size_t)v*HF + f4*4);
    float4 acc = make_float4(0.f, 0.f, 0.f, 0.f);
    int2 rb = rb2[v];
    int e0 = rb.x, e1 = rb.x + rb.y;
    for (int j = e0; j < e1; ++j){
        int2 e = cp[j];
        int s = e.x & (Nn - 1);
        float en = __int_as_float(e.y);
        float4 h = *(const float4*)(Y + (size_t)s*HF + f4*4);
        acc.x += en*h.x; acc.y += en*h.y; acc.z += en*h.z; acc.w += en*h.w;
    }
    int f = f4*4;
    acc.x = y.x*dv*dv + dv*acc.x + cb[f];
    acc.y = y.y*dv*dv + dv*acc.y + cb[f+1];
    acc.z = y.z*dv*dv + dv*acc.z + cb[f+2];
    acc.w = y.w*dv*dv + dv*acc.w + cb[f+3];
    *(float4*)(X + (size_t)v*HF + f) = acc;
}

// ---------------- BN stats (sum, sumsq per column) ----------------
__global__ __launch_bounds__(256) void k_bnstats(const float* __restrict__ X, float* __restrict__ stats){
    int c = threadIdx.x & 127, h = threadIdx.x >> 7;
    int r0 = blockIdx.x * 256;
    float s = 0.f, s2 = 0.f;
    for (int r = r0 + h; r < r0 + 256; r += 2){
        float x = X[(size_t)r*HF + c];
        s += x; s2 += x*x;
    }
    __shared__ float l1[256], l2[256];
    l1[threadIdx.x] = s; l2[threadIdx.x] = s2;
    __syncthreads();
    if (threadIdx.x < 128){
        atomicAdd(&stats[c],     l1[threadIdx.x] + l1[threadIdx.x+128]);
        atomicAdd(&stats[128+c], l2[threadIdx.x] + l2[threadIdx.x+128]);
    }
}

// ---------------- mega-fused per-graph kernel (1024 threads = 16 waves/CU) ----------------
__global__ __launch_bounds__(1024) void k_graph(
    const float* __restrict__ H, const float* __restrict__ stats,
    const float* __restrict__ gw, const float* __restrict__ gb,
    const float* __restrict__ aw, const float* __restrict__ th,
    const int2* __restrict__ rb2, int2* __restrict__ csr, const float* __restrict__ dinv,
    int* __restrict__ srcw, int* __restrict__ dstw, float* __restrict__ wv,
    float* __restrict__ P, float* __restrict__ gacc,
    int2* __restrict__ rb2n, float* __restrict__ dinvn,
    float invN, float ca2, float cc2, float ca3, float cc3,
    int n, int last)
{
    int g = blockIdx.x, t = threadIdx.x;
    int k = n >> 1;
    __shared__ int2  eds[4096];
    __shared__ int2  rbl[512];
    __shared__ float dvv[512], p0[512], p1[512], p2[512];
    __shared__ float ss[512];
    __shared__ int   si[512];
    __shared__ float tss[256];
    __shared__ int   nid[512];
    __shared__ int   cntN[256], curN[256];
    __shared__ float dvn[256];
    __shared__ float bna[128], bnb[128];
    __shared__ float red[1024];

    if (t < 128){
        float mean = stats[t]*invN;
        float var  = stats[128+t]*invN - mean*mean;
        float iv   = rsqrtf(var + 1e-5f);
        bna[t] = iv*gw[t];
        bnb[t] = gb[t] - mean*iv*gw[t];
    }
    for (int l = t; l < n; l += 1024){
        int2 rb = rb2[g*n + l];
        rbl[l] = make_int2(rb.x - g*4096, rb.y);
        dvv[l] = dinv[g*n + l];
    }
    __syncthreads();
    int medg = rbl[n-1].x + rbl[n-1].y;
    for (int j = t; j < medg; j += 1024){
        int2 e = csr[g*4096 + j];
        eds[j] = make_int2(e.x & (n-1), e.y);   // local src, dinv bits
    }
    // s0 per node: one wave per node, shuffle reduce
    int lane = t & 63, wid = t >> 6;           // 16 waves
    for (int l = wid; l < n; l += 16){
        const float* hp = H + ((size_t)g*n + l)*HF;
        float a0 = hp[lane], a1 = hp[lane+64];
        float v0 = fmaxf(a0*bna[lane]    + bnb[lane],    0.f) * aw[lane];
        float v1 = fmaxf(a1*bna[lane+64] + bnb[lane+64], 0.f) * aw[lane+64];
        float p = v0 + v1;
        for (int off = 32; off; off >>= 1) p += __shfl_down(p, off);
        if (lane == 0) p0[l] = p;
    }
    __syncthreads();
    // pvec 1: p1 = 2 * pvec(p0)
    for (int l = t; l < n; l += 1024){
        int2 rc = rbl[l];
        float acc = 0.f;
        for (int j = 0; j < rc.y; ++j){
            int2 e = eds[rc.x + j];
            acc += __int_as_float(e.y) * p0[e.x];
        }
        float dv = dvv[l];
        p1[l] = 2.f*(p0[l]*dv*dv + dv*acc);
    }
    __syncthreads();
    // pvec 2: p2 = ca2*pvec(p1) + cc2*p0
    for (int l = t; l < n; l += 1024){
        int2 rc = rbl[l];
        float acc = 0.f;
        for (int j = 0; j < rc.y; ++j){
            int2 e = eds[rc.x + j];
            acc += __int_as_float(e.y) * p1[e.x];
        }
        float dv = dvv[l];
        p2[l] = ca2*(p1[l]*dv*dv + dv*acc) + cc2*p0[l];
    }
    __syncthreads();
    // pvec 3 + theta combine -> score
    float t0v = th[0], t1v = th[1], t2c = th[2], t3v = th[3];
    for (int l = t; l < n; l += 1024){
        int2 rc = rbl[l];
        float acc = 0.f;
        for (int j = 0; j < rc.y; ++j){
            int2 e = eds[rc.x + j];
            acc += __int_as_float(e.y) * p2[e.x];
        }
        float dv = dvv[l];
        float tv = p2[l]*dv*dv + dv*acc;
        float p3 = ca3*tv + cc3*p1[l];
        ss[l] = t0v*p0[l] + t1v*p1[l] + t2c*p2[l] + t3v*p3;
        si[l] = l;
    }
    __syncthreads();
    // bitonic sort desc by (score, -idx)
    for (int size = 2; size <= n; size <<= 1){
        for (int stride = size >> 1; stride > 0; stride >>= 1){
            for (int i = t; i < n; i += 1024){
                int j = i ^ stride;
                if (j > i){
                    bool asc = ((i & size) == 0);
                    float s1 = ss[i], s2 = ss[j];
                    int   i1 = si[i], i2 = si[j];
                    bool gt = (s1 < s2) || (s1 == s2 && i1 > i2);
                    if (gt == asc){ ss[i] = s2; ss[j] = s1; si[i] = i2; si[j] = i1; }
                }
            }
            __syncthreads();
        }
    }
    for (int l = t; l < n; l += 1024) nid[l] = -1;
    __syncthreads();
    for (int r = t; r < k; r += 1024){
        nid[si[r]] = r;
        tss[r] = tanhf(ss[r]);
    }
    __syncthreads();
    // gather (BN+ReLU on the fly, scale by tanh) + readout max/mean (8 row-groups)
    {
        int f = t & 127, rl = t >> 7;          // rl in 0..7
        float af = bna[f], bf = bnb[f];
        float mx = -3.4e38f, sm = 0.f;
        for (int r = rl; r < k; r += 8){
            int old = si[r];
            float hv = H[((size_t)g*n + old)*HF + f];
            float v = fmaxf(hv*af + bf, 0.f) * tss[r];
            P[((size_t)g*k + r)*HF + f] = v;
            mx = fmaxf(mx, v); sm += v;
        }
        red[t] = mx;
        __syncthreads();
        if (t < 512) red[t] = fmaxf(red[t], red[t+512]);
        __syncthreads();
        if (t < 256) red[t] = fmaxf(red[t], red[t+256]);
        __syncthreads();
        if (t < 128) gacc[g*256 + t] += fmaxf(red[t], red[t+128]);
        __syncthreads();
        red[t] = sm;
        __syncthreads();
        if (t < 512) red[t] += red[t+512];
        __syncthreads();
        if (t < 256) red[t] += red[t+256];
        __syncthreads();
        if (t < 128) gacc[g*256 + 128 + t] += (red[t] + red[t+128]) / (float)k;
    }
    if (last) return;
    __syncthreads();
    // remap edges + next-level CSR build (all block-local)
    if (t < k) cntN[t] = 0;
    __syncthreads();
    for (int j = t; j < 4096; j += 1024){
        int e = g*4096 + j;
        float we = wv[e];
        int valid = 0, ns = 0, nd = 0;
        if (we > 0.5f){
            int sl = srcw[e] & (n-1);
            int dl = dstw[e] & (n-1);
            ns = nid[sl]; nd = nid[dl];
            valid = (ns >= 0) && (nd >= 0);
        }
        if (valid){
            srcw[e] = g*k + ns; dstw[e] = g*k + nd; wv[e] = 1.f;
            atomicAdd(&cntN[nd], 1);
        } else {
            srcw[e] = 0; dstw[e] = 0; wv[e] = 0.f;
        }
    }
    __syncthreads();
    // scan cntN (k <= 256) via si as temp; first 256 threads scan, all hit barriers
    int c = (t < 256) ? ((t < k) ? cntN[t] : 0) : 0;
    if (t < 256) si[t] = c;
    __syncthreads();
    for (int off = 1; off < 256; off <<= 1){
        int a = 0;
        if (t < 256 && t >= off) a = si[t-off];
        __syncthreads();
        if (t < 256) si[t] += a;
        __syncthreads();
    }
    if (t < k){
        int beg = si[t] - c;
        rb2n[g*k + t] = make_int2(g*4096 + beg, c);
        float dv = rsqrtf((float)c + 1.f);
        dinvn[g*k + t] = dv;
        dvn[t] = dv;
        curN[t] = beg;
    }
    __syncthreads();
    for (int j = t; j < 4096; j += 1024){
        int e = g*4096 + j;
        if (wv[e] > 0.5f){
            int sg = srcw[e], dl = dstw[e] & (k-1);
            int p = atomicAdd(&curN[dl], 1);
            csr[g*4096 + p] = make_int2(sg, __float_as_int(dvn[sg & (k-1)]));
        }
    }
}

// ---------------- head (parallel, fully unrolled) ----------------
__global__ __launch_bounds__(256) void k_head1(const float* __restrict__ gacc, const float* __restrict__ W1,
                                               const float* __restrict__ b1, float* __restrict__ t1,
                                               float* __restrict__ sh){
    int r = blockIdx.x;
    int c = threadIdx.x & 127, h = threadIdx.x >> 7;
    __shared__ float gs[256];
    __shared__ float red[256];
    gs[threadIdx.x] = gacc[r*256 + threadIdx.x];
    __syncthreads();
    float s = 0.f;
    #pragma unroll
    for (int kk = 0; kk < 128; ++kk)
        s += gs[h*128 + kk] * W1[(h*128 + kk)*128 + c];
    red[threadIdx.x] = s;
    __syncthreads();
    if (h == 0){
        float v = (red[c] + red[c+128]) * 0.2f + b1[c];
        t1[r*128 + c] = v;
        atomicAdd(&sh[c], v);
        atomicAdd(&sh[128 + c], v*v);
    }
}
__global__ __launch_bounds__(128) void k_head2(const float* __restrict__ t1, const float* __restrict__ gw,
                                               const float* __restrict__ gb, const float* __restrict__ W2,
                                               const float* __restrict__ b2, float* __restrict__ sh,
                                               float* __restrict__ t2){
    int r = blockIdx.x, t = threadIdx.x;
    int cc = t & 63, h = t >> 6;
    __shared__ float row[128];
    __shared__ float red[128];
    {
        float mean = sh[t] * (1.f/128.f);
        float var  = sh[128+t]*(1.f/128.f) - mean*mean;
        float iv   = rsqrtf(var + 1e-5f);
        float v = (t1[r*128+t] - mean)*iv*gw[t] + gb[t];
        row[t] = fmaxf(v, 0.f);
    }
    __syncthreads();
    float s = 0.f;
    #pragma unroll
    for (int kk = 0; kk < 64; ++kk)
        s += row[h*64+kk] * W2[(h*64+kk)*64 + cc];
    red[t] = s;
    __syncthreads();
    if (h == 0){
        float v = red[cc] + red[cc+64] + b2[cc];
        t2[r*64+cc] = v;
        atomicAdd(&sh[256+cc], v);
        atomicAdd(&sh[320+cc], v*v);
    }
}
__global__ __launch_bounds__(64) void k_head3(const float* __restrict__ t2, const float* __restrict__ gw,
                                              const float* __restrict__ gb, const float* __restrict__ W3,
                                              const float* __restrict__ b3, const float* __restrict__ sh,
                                              float* __restrict__ out){
    int r = blockIdx.x, t = threadIdx.x;
    float mean = sh[256+t]*(1.f/128.f);
    float var  = sh[320+t]*(1.f/128.f) - mean*mean;
    float iv   = rsqrtf(var + 1e-5f);
    float v = fmaxf((t2[r*64+t]-mean)*iv*gw[t] + gb[t], 0.f);
    float lg[10];
    #pragma unroll
    for (int j = 0; j < 10; ++j){
        float p = v * W3[t*10 + j];
        for (int off = 32; off; off >>= 1) p += __shfl_down(p, off);
        lg[j] = p;
    }
    if (t == 0){
        float m = -3.4e38f;
        #pragma unroll
        for (int j = 0; j < 10; ++j){ lg[j] += b3[j]; m = fmaxf(m, lg[j]); }
        float se = 0.f;
        #pragma unroll
        for (int j = 0; j < 10; ++j) se += expf(lg[j] - m);
        float l = logf(se) + m;
        #pragma unroll
        for (int j = 0; j < 10; ++j) out[r*10 + j] = lg[j] - l;
    }
}

extern "C" void kernel_launch(void* const* d_in, const int* in_sizes, int n_in,
                              void* d_out, int out_size, void* d_ws, size_t ws_size,
                              hipStream_t stream){
    const float* x     = (const float*)d_in[0];
    const float* convW = (const float*)d_in[1];
    const float* convb = (const float*)d_in[2];
    const float* bnW   = (const float*)d_in[3];
    const float* bnB   = (const float*)d_in[4];
    const float* bn7W  = (const float*)d_in[5];
    const float* bn7B  = (const float*)d_in[6];
    const float* attW  = (const float*)d_in[7];
    const float* theta = (const float*)d_in[8];
    const float* lin1W = (const float*)d_in[9];
    const float* lin1b = (const float*)d_in[10];
    const float* lin2W = (const float*)d_in[11];
    const float* lin2b = (const float*)d_in[12];
    const float* lin3W = (const float*)d_in[13];
    const float* lin3b = (const float*)d_in[14];
    const int*   src0  = (const int*)d_in[15];
    const int*   dst0  = (const int*)d_in[16];

    char* base = (char*)d_ws;
    size_t off = 0;
    auto take = [&](size_t bytes) -> void* {
        void* p = base + off;
        off = (off + bytes + 255) & ~(size_t)255;
        return p;
    };
    float* bufGP = (float*)take((size_t)N0G*HF*4);
    float* bufH  = (float*)take((size_t)N0G*HF*4);
    int*   srcw  = (int*)  take((size_t)ETOT*4);
    int*   dstw  = (int*)  take((size_t)ETOT*4);
    float* w     = (float*)take((size_t)ETOT*4);
    int2*  csr_p = (int2*) take((size_t)ETOT*8);
    int2*  rb2A  = (int2*) take((size_t)N0G*8);
    int2*  rb2B  = (int2*) take((size_t)N0G*8);
    float* dinvA = (float*)take((size_t)N0G*4);
    float* dinvB = (float*)take((size_t)N0G*4);
    float* stats = (float*)take(256*4);
    float* gacc  = (float*)take((size_t)B_GRAPH*256*4);
    float* t1    = (float*)take((size_t)B_GRAPH*128*4);
    float* t2    = (float*)take((size_t)B_GRAPH*64*4);
    float* statsH= (float*)take(384*4);

    auto coef = [](int kk, float& ca, float& cc){
        double a = 1.0, b = 1.0;
        double c0 = 2.0*kk*(kk+a+b)*(2.0*kk+a+b-2.0);
        double c1 = (2.0*kk+a+b-1.0)*(2.0*kk+a+b)*(2.0*kk+a+b-2.0);
        double c3 = 2.0*(kk+a-1.0)*(kk+b-1.0)*(2.0*kk+a+b);
        ca = (float)(c1/c0); cc = (float)(-c3/c0);
    };
    float ca2, cc2, ca3, cc3;
    coef(2, ca2, cc2);
    coef(3, ca3, cc3);

    k_init<<<B_GRAPH, 256, 0, stream>>>(src0, dst0, srcw, dstw, w, csr_p, rb2A, dinvA, gacc, statsH);

    for (int i = 0; i < 5; ++i){
        int n = 512 >> i;
        int Nn = B_GRAPH*n;
        int lb = 6 - i;
        int2*  rb_cur = (i & 1) ? rb2B : rb2A;
        int2*  rb_nxt = (i & 1) ? rb2A : rb2B;
        float* dv_cur = (i & 1) ? dinvB : dinvA;
        float* dv_nxt = (i & 1) ? dinvA : dinvB;
        const float* gemmA = (i == 0) ? x : bufGP;
        float* G = (i == 0) ? bufGP : (bufGP + (size_t)4*1024*1024);

        k_gemm<<<Nn/64, 256, 0, stream>>>(gemmA, convW + (size_t)i*HF*HF, G, stats);
        k_prop<<<Nn/8, 256, 0, stream>>>(G, convb + i*HF, rb_cur, csr_p, dv_cur, bufH, n, lb, Nn);
        k_bnstats<<<Nn/256, 256, 0, stream>>>(bufH, stats);
        k_graph<<<B_GRAPH, 1024, 0, stream>>>(bufH, stats, bnW + i*HF, bnB + i*HF, attW + i*HF,
                                              theta + i*4, rb_cur, csr_p, dv_cur,
                                              srcw, dstw, w, bufGP, gacc, rb_nxt, dv_nxt,
                                              1.0f/(float)Nn, ca2, cc2, ca3, cc3, n, (i == 4) ? 1 : 0);
    }

    k_head1<<<B_GRAPH, 256, 0, stream>>>(gacc, lin1W, lin1b, t1, statsH);
    k_head2<<<B_GRAPH, 128, 0, stream>>>(t1, bnW + 5*HF, bnB + 5*HF, lin2W, lin2b, statsH, t2);
    k_head3<<<B_GRAPH, 64, 0, stream>>>(t2, bn7W, bn7B, lin3W, lin3b, statsH, (float*)d_out);
}

// Round 8
// 524.350 us; speedup vs baseline: 2.2049x; 1.1154x over previous
//
#include <hip/hip_runtime.h>
#include <hip/hip_bf16.h>

#define B_GRAPH 128
#define ETOT    (128*4096)   // 524288 edges (static)
#define N0G     (128*512)    // 65536 nodes at level 0
#define HF      128

// ---------------- level-0 init: copy edges, w=1, per-graph CSR build, zero gacc/stats ----------------
__global__ __launch_bounds__(256) void k_init(const int* __restrict__ s_in, const int* __restrict__ d_in_,
                                              int* __restrict__ srcw, int* __restrict__ dstw,
                                              float* __restrict__ wv, int2* __restrict__ csr,
                                              int2* __restrict__ rb2, float* __restrict__ dinvv,
                                              float* __restrict__ gacc, float* __restrict__ statsH,
                                              float* __restrict__ stats0, float* __restrict__ stats1){
    int g = blockIdx.x, t = threadIdx.x;
    __shared__ int cnt[512];
    __shared__ int cur[512];
    __shared__ float dvl[512];
    for (int l = t; l < 512; l += 256) cnt[l] = 0;
    gacc[g*256 + t] = 0.f;
    if (g == 0){
        statsH[t] = 0.f; if (t < 128) statsH[256+t] = 0.f;
        stats0[t] = 0.f; stats1[t] = 0.f;
    }
    __syncthreads();
    for (int j = t; j < 4096; j += 256){
        int e = g*4096 + j;
        int sg = s_in[e], dg = d_in_[e];
        srcw[e] = sg; dstw[e] = dg; wv[e] = 1.f;
        atomicAdd(&cnt[dg & 511], 1);
    }
    __syncthreads();
    int c0 = cnt[2*t], c1 = cnt[2*t+1];
    int pairsum = c0 + c1;
    cur[t] = pairsum;
    __syncthreads();
    for (int off = 1; off < 256; off <<= 1){
        int a = (t >= off) ? cur[t-off] : 0;
        __syncthreads();
        cur[t] += a;
        __syncthreads();
    }
    int begpair = cur[t] - pairsum;
    __syncthreads();
    cur[2*t]   = begpair;
    cur[2*t+1] = begpair + c0;
    __syncthreads();
    for (int l = t; l < 512; l += 256){
        rb2[g*512 + l] = make_int2(g*4096 + cur[l], cnt[l]);
        float dv = rsqrtf((float)cnt[l] + 1.f);
        dvl[l] = dv;
        dinvv[g*512 + l] = dv;
    }
    __syncthreads();
    for (int j = t; j < 4096; j += 256){
        int e = g*4096 + j;
        int sg = srcw[e], dl = dstw[e] & 511;
        int p = atomicAdd(&cur[dl], 1);
        csr[g*4096 + p] = make_int2(sg, __float_as_int(dvl[sg & 511]));
    }
}

// ---------------- fused per-graph conv: GEMM + prop + BN-stats accumulate ----------------
// One block per graph. Phase 1: G = A@W (W 64-row halves in LDS, identical FMA order to old k_gemm).
// Phase 2: prop gathers neighbor rows of G (written by THIS block -> XCD-local L2). Phase 3: stats.
__global__ __launch_bounds__(1024, 4) void k_conv(
    const float* __restrict__ A, const float* __restrict__ Wg, const float* __restrict__ cb,
    const int2* __restrict__ rb2, const int2* __restrict__ cp, const float* __restrict__ dinv,
    float* __restrict__ G, float* __restrict__ X, float* __restrict__ stats,
    int n, int Nn)
{
    int g = blockIdx.x, t = threadIdx.x;
    __shared__ float Ws[64*HF];      // 32 KB
    __shared__ float red[32*HF];     // 16 KB
    // ---- phase 1: GEMM (row tiles of 256 = 4 sub-blocks x 64 rows) ----
    int sub = t >> 8;                // 0..3
    int t8  = t & 255;
    int tx = t8 & 15, ty = t8 >> 4;
    int nT = (n + 255) >> 8;
    for (int tile = 0; tile < nT; ++tile){
        int r0 = tile*256 + sub*64 + ty*4;
        bool act = (r0 < n);
        float acc[4][8];
        #pragma unroll
        for (int j=0;j<4;++j)
            #pragma unroll
            for (int l=0;l<8;++l) acc[j][l] = 0.f;
        for (int kh = 0; kh < 2; ++kh){
            __syncthreads();
            {
                float4* d4 = (float4*)Ws;
                const float4* s4 = (const float4*)(Wg + kh*64*HF);
                #pragma unroll
                for (int i = 0; i < 2; ++i) d4[t + i*1024] = s4[t + i*1024];
            }
            __syncthreads();
            if (act){
                int c0 = tx*4;
                for (int k4 = 0; k4 < 16; ++k4){
                    float4 av[4];
                    #pragma unroll
                    for (int j=0;j<4;++j)
                        av[j] = *(const float4*)(A + ((size_t)g*n + r0 + j)*HF + kh*64 + k4*4);
                    #pragma unroll
                    for (int kk=0; kk<4; ++kk){
                        int kl = k4*4 + kk;
                        float4 w0 = *(const float4*)(Ws + kl*HF + c0);
                        float4 w1 = *(const float4*)(Ws + kl*HF + c0 + 64);
                        #pragma unroll
                        for (int j=0;j<4;++j){
                            float a = reinterpret_cast<const float*>(&av[j])[kk];
                            acc[j][0] += a*w0.x; acc[j][1] += a*w0.y; acc[j][2] += a*w0.z; acc[j][3] += a*w0.w;
                            acc[j][4] += a*w1.x; acc[j][5] += a*w1.y; acc[j][6] += a*w1.z; acc[j][7] += a*w1.w;
                        }
                    }
                }
            }
        }
        if (act){
            int c0 = tx*4;
            #pragma unroll
            for (int j=0;j<4;++j){
                *(float4*)(G + ((size_t)g*n + r0 + j)*HF + c0)      = make_float4(acc[j][0],acc[j][1],acc[j][2],acc[j][3]);
                *(float4*)(G + ((size_t)g*n + r0 + j)*HF + c0 + 64) = make_float4(acc[j][4],acc[j][5],acc[j][6],acc[j][7]);
            }
        }
    }
    __syncthreads();   // drains vmcnt -> G visible to whole block
    // ---- phase 2: prop + per-thread stats partials ----
    int f4 = t & 31;
    int f = f4*4;
    float4 s  = make_float4(0.f,0.f,0.f,0.f);
    float4 s2 = make_float4(0.f,0.f,0.f,0.f);
    float cb0 = cb[f], cb1 = cb[f+1], cb2 = cb[f+2], cb3 = cb[f+3];
    for (int l = t >> 5; l < n; l += 32){
        int v = g*n + l;
        float dv = dinv[v];
        float4 y = *(const float4*)(G + (size_t)v*HF + f);
        float4 acc = make_float4(0.f,0.f,0.f,0.f);
        int2 rb = rb2[v];
        int e0 = rb.x, e1 = rb.x + rb.y;
        for (int j = e0; j < e1; ++j){
            int2 e = cp[j];
            int sN = e.x & (Nn - 1);
            float en = __int_as_float(e.y);
            float4 h = *(const float4*)(G + (size_t)sN*HF + f);
            acc.x += en*h.x; acc.y += en*h.y; acc.z += en*h.z; acc.w += en*h.w;
        }
        acc.x = y.x*dv*dv + dv*acc.x + cb0;
        acc.y = y.y*dv*dv + dv*acc.y + cb1;
        acc.z = y.z*dv*dv + dv*acc.z + cb2;
        acc.w = y.w*dv*dv + dv*acc.w + cb3;
        *(float4*)(X + (size_t)v*HF + f) = acc;
        s.x += acc.x; s.y += acc.y; s.z += acc.z; s.w += acc.w;
        s2.x += acc.x*acc.x; s2.y += acc.y*acc.y; s2.z += acc.z*acc.z; s2.w += acc.w*acc.w;
    }
    // ---- phase 3: stats reduce (sum then sumsq) ----
    int base = (t >> 5)*HF + f;
    __syncthreads();
    *(float4*)&red[base] = s;
    __syncthreads();
    if (t < 128){
        float a = 0.f;
        #pragma unroll
        for (int j = 0; j < 32; ++j) a += red[j*HF + t];
        atomicAdd(&stats[t], a);
    }
    __syncthreads();
    *(float4*)&red[base] = s2;
    __syncthreads();
    if (t < 128){
        float a = 0.f;
        #pragma unroll
        for (int j = 0; j < 32; ++j) a += red[j*HF + t];
        atomicAdd(&stats[128+t], a);
    }
}

// ---------------- mega-fused per-graph kernel (1024 threads) ----------------
__global__ __launch_bounds__(1024) void k_graph(
    const float* __restrict__ H, const float* __restrict__ stats,
    const float* __restrict__ gw, const float* __restrict__ gb,
    const float* __restrict__ aw, const float* __restrict__ th,
    const int2* __restrict__ rb2, int2* __restrict__ csr, const float* __restrict__ dinv,
    int* __restrict__ srcw, int* __restrict__ dstw, float* __restrict__ wv,
    float* __restrict__ P, float* __restrict__ gacc,
    int2* __restrict__ rb2n, float* __restrict__ dinvn, float* __restrict__ statsNext,
    float invN, float ca2, float cc2, float ca3, float cc3,
    int n, int last)
{
    int g = blockIdx.x, t = threadIdx.x;
    int k = n >> 1;
    __shared__ int2  eds[4096];
    __shared__ int2  rbl[512];
    __shared__ float dvv[512], p0[512], p1[512], p2[512];
    __shared__ float ss[512];
    __shared__ int   si[512];
    __shared__ float tss[256];
    __shared__ int   nid[512];
    __shared__ int   cntN[256], curN[256];
    __shared__ float dvn[256];
    __shared__ float bna[128], bnb[128];
    __shared__ float red[1024];

    if (t < 256) statsNext[t] = 0.f;    // zero next level's stats buffer (A(i+1) runs strictly later)
    if (t < 128){
        float mean = stats[t]*invN;
        float var  = stats[128+t]*invN - mean*mean;
        float iv   = rsqrtf(var + 1e-5f);
        bna[t] = iv*gw[t];
        bnb[t] = gb[t] - mean*iv*gw[t];
    }
    for (int l = t; l < n; l += 1024){
        int2 rb = rb2[g*n + l];
        rbl[l] = make_int2(rb.x - g*4096, rb.y);
        dvv[l] = dinv[g*n + l];
    }
    __syncthreads();
    int medg = rbl[n-1].x + rbl[n-1].y;
    for (int j = t; j < medg; j += 1024){
        int2 e = csr[g*4096 + j];
        eds[j] = make_int2(e.x & (n-1), e.y);
    }
    int lane = t & 63, wid = t >> 6;
    for (int l = wid; l < n; l += 16){
        const float* hp = H + ((size_t)g*n + l)*HF;
        float a0 = hp[lane], a1 = hp[lane+64];
        float v0 = fmaxf(a0*bna[lane]    + bnb[lane],    0.f) * aw[lane];
        float v1 = fmaxf(a1*bna[lane+64] + bnb[lane+64], 0.f) * aw[lane+64];
        float p = v0 + v1;
        for (int off = 32; off; off >>= 1) p += __shfl_down(p, off);
        if (lane == 0) p0[l] = p;
    }
    __syncthreads();
    for (int l = t; l < n; l += 1024){
        int2 rc = rbl[l];
        float acc = 0.f;
        for (int j = 0; j < rc.y; ++j){
            int2 e = eds[rc.x + j];
            acc += __int_as_float(e.y) * p0[e.x];
        }
        float dv = dvv[l];
        p1[l] = 2.f*(p0[l]*dv*dv + dv*acc);
    }
    __syncthreads();
    for (int l = t; l < n; l += 1024){
        int2 rc = rbl[l];
        float acc = 0.f;
        for (int j = 0; j < rc.y; ++j){
            int2 e = eds[rc.x + j];
            acc += __int_as_float(e.y) * p1[e.x];
        }
        float dv = dvv[l];
        p2[l] = ca2*(p1[l]*dv*dv + dv*acc) + cc2*p0[l];
    }
    __syncthreads();
    float t0v = th[0], t1v = th[1], t2c = th[2], t3v = th[3];
    for (int l = t; l < n; l += 1024){
        int2 rc = rbl[l];
        float acc = 0.f;
        for (int j = 0; j < rc.y; ++j){
            int2 e = eds[rc.x + j];
            acc += __int_as_float(e.y) * p2[e.x];
        }
        float dv = dvv[l];
        float tv = p2[l]*dv*dv + dv*acc;
        float p3 = ca3*tv + cc3*p1[l];
        ss[l] = t0v*p0[l] + t1v*p1[l] + t2c*p2[l] + t3v*p3;
        si[l] = l;
    }
    __syncthreads();
    for (int size = 2; size <= n; size <<= 1){
        for (int stride = size >> 1; stride > 0; stride >>= 1){
            for (int i = t; i < n; i += 1024){
                int j = i ^ stride;
                if (j > i){
                    bool asc = ((i & size) == 0);
                    float s1 = ss[i], s2 = ss[j];
                    int   i1 = si[i], i2 = si[j];
                    bool gt = (s1 < s2) || (s1 == s2 && i1 > i2);
                    if (gt == asc){ ss[i] = s2; ss[j] = s1; si[i] = i2; si[j] = i1; }
                }
            }
            __syncthreads();
        }
    }
    for (int l = t; l < n; l += 1024) nid[l] = -1;
    __syncthreads();
    for (int r = t; r < k; r += 1024){
        nid[si[r]] = r;
        tss[r] = tanhf(ss[r]);
    }
    __syncthreads();
    {
        int f = t & 127, rl = t >> 7;
        float af = bna[f], bf = bnb[f];
        float mx = -3.4e38f, sm = 0.f;
        for (int r = rl; r < k; r += 8){
            int old = si[r];
            float hv = H[((size_t)g*n + old)*HF + f];
            float v = fmaxf(hv*af + bf, 0.f) * tss[r];
            P[((size_t)g*k + r)*HF + f] = v;
            mx = fmaxf(mx, v); sm += v;
        }
        red[t] = mx;
        __syncthreads();
        if (t < 512) red[t] = fmaxf(red[t], red[t+512]);
        __syncthreads();
        if (t < 256) red[t] = fmaxf(red[t], red[t+256]);
        __syncthreads();
        if (t < 128) gacc[g*256 + t] += fmaxf(red[t], red[t+128]);
        __syncthreads();
        red[t] = sm;
        __syncthreads();
        if (t < 512) red[t] += red[t+512];
        __syncthreads();
        if (t < 256) red[t] += red[t+256];
        __syncthreads();
        if (t < 128) gacc[g*256 + 128 + t] += (red[t] + red[t+128]) / (float)k;
    }
    if (last) return;
    __syncthreads();
    if (t < k) cntN[t] = 0;
    __syncthreads();
    for (int j = t; j < 4096; j += 1024){
        int e = g*4096 + j;
        float we = wv[e];
        int valid = 0, ns = 0, nd = 0;
        if (we > 0.5f){
            int sl = srcw[e] & (n-1);
            int dl = dstw[e] & (n-1);
            ns = nid[sl]; nd = nid[dl];
            valid = (ns >= 0) && (nd >= 0);
        }
        if (valid){
            srcw[e] = g*k + ns; dstw[e] = g*k + nd; wv[e] = 1.f;
            atomicAdd(&cntN[nd], 1);
        } else {
            srcw[e] = 0; dstw[e] = 0; wv[e] = 0.f;
        }
    }
    __syncthreads();
    int c = (t < 256) ? ((t < k) ? cntN[t] : 0) : 0;
    if (t < 256) si[t] = c;
    __syncthreads();
    for (int off = 1; off < 256; off <<= 1){
        int a = 0;
        if (t < 256 && t >= off) a = si[t-off];
        __syncthreads();
        if (t < 256) si[t] += a;
        __syncthreads();
    }
    if (t < k){
        int beg = si[t] - c;
        rb2n[g*k + t] = make_int2(g*4096 + beg, c);
        float dv = rsqrtf((float)c + 1.f);
        dinvn[g*k + t] = dv;
        dvn[t] = dv;
        curN[t] = beg;
    }
    __syncthreads();
    for (int j = t; j < 4096; j += 1024){
        int e = g*4096 + j;
        if (wv[e] > 0.5f){
            int sg = srcw[e], dl = dstw[e] & (k-1);
            int p = atomicAdd(&curN[dl], 1);
            csr[g*4096 + p] = make_int2(sg, __float_as_int(dvn[sg & (k-1)]));
        }
    }
}

// ---------------- head ----------------
__global__ __launch_bounds__(256) void k_head1(const float* __restrict__ gacc, const float* __restrict__ W1,
                                               const float* __restrict__ b1, float* __restrict__ t1,
                                               float* __restrict__ sh){
    int r = blockIdx.x;
    int c = threadIdx.x & 127, h = threadIdx.x >> 7;
    __shared__ float gs[256];
    __shared__ float red[256];
    gs[threadIdx.x] = gacc[r*256 + threadIdx.x];
    __syncthreads();
    float s = 0.f;
    #pragma unroll
    for (int kk = 0; kk < 128; ++kk)
        s += gs[h*128 + kk] * W1[(h*128 + kk)*128 + c];
    red[threadIdx.x] = s;
    __syncthreads();
    if (h == 0){
        float v = (red[c] + red[c+128]) * 0.2f + b1[c];
        t1[r*128 + c] = v;
        atomicAdd(&sh[c], v);
        atomicAdd(&sh[128 + c], v*v);
    }
}
__global__ __launch_bounds__(128) void k_head2(const float* __restrict__ t1, const float* __restrict__ gw,
                                               const float* __restrict__ gb, const float* __restrict__ W2,
                                               const float* __restrict__ b2, float* __restrict__ sh,
                                               float* __restrict__ t2){
    int r = blockIdx.x, t = threadIdx.x;
    int cc = t & 63, h = t >> 6;
    __shared__ float row[128];
    __shared__ float red[128];
    {
        float mean = sh[t] * (1.f/128.f);
        float var  = sh[128+t]*(1.f/128.f) - mean*mean;
        float iv   = rsqrtf(var + 1e-5f);
        float v = (t1[r*128+t] - mean)*iv*gw[t] + gb[t];
        row[t] = fmaxf(v, 0.f);
    }
    __syncthreads();
    float s = 0.f;
    #pragma unroll
    for (int kk = 0; kk < 64; ++kk)
        s += row[h*64+kk] * W2[(h*64+kk)*64 + cc];
    red[t] = s;
    __syncthreads();
    if (h == 0){
        float v = red[cc] + red[cc+64] + b2[cc];
        t2[r*64+cc] = v;
        atomicAdd(&sh[256+cc], v);
        atomicAdd(&sh[320+cc], v*v);
    }
}
__global__ __launch_bounds__(64) void k_head3(const float* __restrict__ t2, const float* __restrict__ gw,
                                              const float* __restrict__ gb, const float* __restrict__ W3,
                                              const float* __restrict__ b3, const float* __restrict__ sh,
                                              float* __restrict__ out){
    int r = blockIdx.x, t = threadIdx.x;
    float mean = sh[256+t]*(1.f/128.f);
    float var  = sh[320+t]*(1.f/128.f) - mean*mean;
    float iv   = rsqrtf(var + 1e-5f);
    float v = fmaxf((t2[r*64+t]-mean)*iv*gw[t] + gb[t], 0.f);
    float lg[10];
    #pragma unroll
    for (int j = 0; j < 10; ++j){
        float p = v * W3[t*10 + j];
        for (int off = 32; off; off >>= 1) p += __shfl_down(p, off);
        lg[j] = p;
    }
    if (t == 0){
        float m = -3.4e38f;
        #pragma unroll
        for (int j = 0; j < 10; ++j){ lg[j] += b3[j]; m = fmaxf(m, lg[j]); }
        float se = 0.f;
        #pragma unroll
        for (int j = 0; j < 10; ++j) se += expf(lg[j] - m);
        float l = logf(se) + m;
        #pragma unroll
        for (int j = 0; j < 10; ++j) out[r*10 + j] = lg[j] - l;
    }
}

extern "C" void kernel_launch(void* const* d_in, const int* in_sizes, int n_in,
                              void* d_out, int out_size, void* d_ws, size_t ws_size,
                              hipStream_t stream){
    const float* x     = (const float*)d_in[0];
    const float* convW = (const float*)d_in[1];
    const float* convb = (const float*)d_in[2];
    const float* bnW   = (const float*)d_in[3];
    const float* bnB   = (const float*)d_in[4];
    const float* bn7W  = (const float*)d_in[5];
    const float* bn7B  = (const float*)d_in[6];
    const float* attW  = (const float*)d_in[7];
    const float* theta = (const float*)d_in[8];
    const float* lin1W = (const float*)d_in[9];
    const float* lin1b = (const float*)d_in[10];
    const float* lin2W = (const float*)d_in[11];
    const float* lin2b = (const float*)d_in[12];
    const float* lin3W = (const float*)d_in[13];
    const float* lin3b = (const float*)d_in[14];
    const int*   src0  = (const int*)d_in[15];
    const int*   dst0  = (const int*)d_in[16];

    char* base = (char*)d_ws;
    size_t off = 0;
    auto take = [&](size_t bytes) -> void* {
        void* p = base + off;
        off = (off + bytes + 255) & ~(size_t)255;
        return p;
    };
    float* bufGP = (float*)take((size_t)N0G*HF*4);
    float* bufH  = (float*)take((size_t)N0G*HF*4);
    int*   srcw  = (int*)  take((size_t)ETOT*4);
    int*   dstw  = (int*)  take((size_t)ETOT*4);
    float* w     = (float*)take((size_t)ETOT*4);
    int2*  csr_p = (int2*) take((size_t)ETOT*8);
    int2*  rb2A  = (int2*) take((size_t)N0G*8);
    int2*  rb2B  = (int2*) take((size_t)N0G*8);
    float* dinvA = (float*)take((size_t)N0G*4);
    float* dinvB = (float*)take((size_t)N0G*4);
    float* stats0= (float*)take(256*4);
    float* stats1= (float*)take(256*4);
    float* gacc  = (float*)take((size_t)B_GRAPH*256*4);
    float* t1    = (float*)take((size_t)B_GRAPH*128*4);
    float* t2    = (float*)take((size_t)B_GRAPH*64*4);
    float* statsH= (float*)take(384*4);

    auto coef = [](int kk, float& ca, float& cc){
        double a = 1.0, b = 1.0;
        double c0 = 2.0*kk*(kk+a+b)*(2.0*kk+a+b-2.0);
        double c1 = (2.0*kk+a+b-1.0)*(2.0*kk+a+b)*(2.0*kk+a+b-2.0);
        double c3 = 2.0*(kk+a-1.0)*(kk+b-1.0)*(2.0*kk+a+b);
        ca = (float)(c1/c0); cc = (float)(-c3/c0);
    };
    float ca2, cc2, ca3, cc3;
    coef(2, ca2, cc2);
    coef(3, ca3, cc3);

    k_init<<<B_GRAPH, 256, 0, stream>>>(src0, dst0, srcw, dstw, w, csr_p, rb2A, dinvA,
                                        gacc, statsH, stats0, stats1);

    for (int i = 0; i < 5; ++i){
        int n = 512 >> i;
        int Nn = B_GRAPH*n;
        int2*  rb_cur = (i & 1) ? rb2B : rb2A;
        int2*  rb_nxt = (i & 1) ? rb2A : rb2B;
        float* dv_cur = (i & 1) ? dinvB : dinvA;
        float* dv_nxt = (i & 1) ? dinvA : dinvB;
        float* st_cur = (i & 1) ? stats1 : stats0;
        float* st_nxt = (i & 1) ? stats0 : stats1;
        const float* convA = (i == 0) ? x : bufGP;
        float* G = (i == 0) ? bufGP : (bufGP + (size_t)4*1024*1024);

        k_conv<<<B_GRAPH, 1024, 0, stream>>>(convA, convW + (size_t)i*HF*HF, convb + i*HF,
                                             rb_cur, csr_p, dv_cur, G, bufH, st_cur, n, Nn);
        k_graph<<<B_GRAPH, 1024, 0, stream>>>(bufH, st_cur, bnW + i*HF, bnB + i*HF, attW + i*HF,
                                              theta + i*4, rb_cur, csr_p, dv_cur,
                                              srcw, dstw, w, bufGP, gacc, rb_nxt, dv_nxt, st_nxt,
                                              1.0f/(float)Nn, ca2, cc2, ca3, cc3, n, (i == 4) ? 1 : 0);
    }

    k_head1<<<B_GRAPH, 256, 0, stream>>>(gacc, lin1W, lin1b, t1, statsH);
    k_head2<<<B_GRAPH, 128, 0, stream>>>(t1, bnW + 5*HF, bnB + 5*HF, lin2W, lin2b, statsH, t2);
    k_head3<<<B_GRAPH, 64, 0, stream>>>(t2, bn7W, bn7B, lin3W, lin3b, statsH, (float*)d_out);
}

// Round 9
// 484.789 us; speedup vs baseline: 2.3848x; 1.0816x over previous
//
#include <hip/hip_runtime.h>
#include <hip/hip_bf16.h>

#define B_GRAPH 128
#define ETOT    (128*4096)   // 524288 edges (static)
#define N0G     (128*512)    // 65536 nodes at level 0
#define HF      128

// ---------------- level-0 init: copy edges, w=1, per-graph CSR build, zero gacc/stats ----------------
__global__ __launch_bounds__(256) void k_init(const int* __restrict__ s_in, const int* __restrict__ d_in_,
                                              int* __restrict__ srcw, int* __restrict__ dstw,
                                              float* __restrict__ wv, int2* __restrict__ csr,
                                              int2* __restrict__ rb2, float* __restrict__ dinvv,
                                              float* __restrict__ gacc, float* __restrict__ statsH,
                                              float* __restrict__ stats0, float* __restrict__ stats1){
    int g = blockIdx.x, t = threadIdx.x;
    __shared__ int cnt[512];
    __shared__ int cur[512];
    __shared__ float dvl[512];
    for (int l = t; l < 512; l += 256) cnt[l] = 0;
    gacc[g*256 + t] = 0.f;
    if (g == 0){
        statsH[t] = 0.f; if (t < 128) statsH[256+t] = 0.f;
        stats0[t] = 0.f; stats1[t] = 0.f;
    }
    __syncthreads();
    for (int j = t; j < 4096; j += 256){
        int e = g*4096 + j;
        int sg = s_in[e], dg = d_in_[e];
        srcw[e] = sg; dstw[e] = dg; wv[e] = 1.f;
        atomicAdd(&cnt[dg & 511], 1);
    }
    __syncthreads();
    int c0 = cnt[2*t], c1 = cnt[2*t+1];
    int pairsum = c0 + c1;
    cur[t] = pairsum;
    __syncthreads();
    for (int off = 1; off < 256; off <<= 1){
        int a = (t >= off) ? cur[t-off] : 0;
        __syncthreads();
        cur[t] += a;
        __syncthreads();
    }
    int begpair = cur[t] - pairsum;
    __syncthreads();
    cur[2*t]   = begpair;
    cur[2*t+1] = begpair + c0;
    __syncthreads();
    for (int l = t; l < 512; l += 256){
        rb2[g*512 + l] = make_int2(g*4096 + cur[l], cnt[l]);
        float dv = rsqrtf((float)cnt[l] + 1.f);
        dvl[l] = dv;
        dinvv[g*512 + l] = dv;
    }
    __syncthreads();
    for (int j = t; j < 4096; j += 256){
        int e = g*4096 + j;
        int sg = srcw[e], dl = dstw[e] & 511;
        int p = atomicAdd(&cur[dl], 1);
        csr[g*4096 + p] = make_int2(sg, __float_as_int(dvl[sg & 511]));
    }
}

// ---------------- chip-wide GEMM (level 0): C[N,128] = A[N,128] @ W[128,128] ----------------
__global__ __launch_bounds__(256) void k_gemm(const float* __restrict__ A, const float* __restrict__ Wg,
                                              float* __restrict__ C){
    __shared__ float Ws[64*HF];
    int tx = threadIdx.x & 15, ty = threadIdx.x >> 4;
    int r0 = blockIdx.x*64 + ty*4, c0 = tx*4;
    float acc[4][8];
    #pragma unroll
    for (int j=0;j<4;++j)
        #pragma unroll
        for (int l=0;l<8;++l) acc[j][l] = 0.f;
    for (int kh = 0; kh < 2; ++kh){
        __syncthreads();
        {
            float4* d4 = (float4*)Ws;
            const float4* s4 = (const float4*)(Wg + kh*64*HF);
            for (int i = threadIdx.x; i < 64*HF/4; i += 256) d4[i] = s4[i];
        }
        __syncthreads();
        for (int k4 = 0; k4 < 16; ++k4){
            float4 av[4];
            #pragma unroll
            for (int j=0;j<4;++j)
                av[j] = *(const float4*)(A + (size_t)(r0+j)*HF + kh*64 + k4*4);
            #pragma unroll
            for (int kk=0; kk<4; ++kk){
                int kl = k4*4 + kk;
                float4 w0 = *(const float4*)(Ws + kl*HF + c0);
                float4 w1 = *(const float4*)(Ws + kl*HF + c0 + 64);
                #pragma unroll
                for (int j=0;j<4;++j){
                    float a = reinterpret_cast<const float*>(&av[j])[kk];
                    acc[j][0] += a*w0.x; acc[j][1] += a*w0.y; acc[j][2] += a*w0.z; acc[j][3] += a*w0.w;
                    acc[j][4] += a*w1.x; acc[j][5] += a*w1.y; acc[j][6] += a*w1.z; acc[j][7] += a*w1.w;
                }
            }
        }
    }
    #pragma unroll
    for (int j=0;j<4;++j){
        *(float4*)(C + (size_t)(r0+j)*HF + c0)      = make_float4(acc[j][0],acc[j][1],acc[j][2],acc[j][3]);
        *(float4*)(C + (size_t)(r0+j)*HF + c0 + 64) = make_float4(acc[j][4],acc[j][5],acc[j][6],acc[j][7]);
    }
}

// ---------------- chip-wide prop (level 0, XCD swizzle) ----------------
__global__ __launch_bounds__(256) void k_prop(const float* __restrict__ Y, const float* __restrict__ cb,
                                              const int2* __restrict__ rb2, const int2* __restrict__ cp,
                                              const float* __restrict__ dinv,
                                              float* __restrict__ X, int n, int lb, int Nn){
    int xcd = blockIdx.x & 7, c = blockIdx.x >> 3;
    int g = xcd*16 + (c >> lb);
    int m = c & ((1 << lb) - 1);
    int v = g*n + m*8 + (threadIdx.x >> 5);
    int f4 = threadIdx.x & 31;
    float dv = dinv[v];
    float4 y = *(const float4*)(Y + (size_t)v*HF + f4*4);
    float4 acc = make_float4(0.f, 0.f, 0.f, 0.f);
    int2 rb = rb2[v];
    int e0 = rb.x, e1 = rb.x + rb.y;
    for (int j = e0; j < e1; ++j){
        int2 e = cp[j];
        int s = e.x & (Nn - 1);
        float en = __int_as_float(e.y);
        float4 h = *(const float4*)(Y + (size_t)s*HF + f4*4);
        acc.x += en*h.x; acc.y += en*h.y; acc.z += en*h.z; acc.w += en*h.w;
    }
    int f = f4*4;
    acc.x = y.x*dv*dv + dv*acc.x + cb[f];
    acc.y = y.y*dv*dv + dv*acc.y + cb[f+1];
    acc.z = y.z*dv*dv + dv*acc.z + cb[f+2];
    acc.w = y.w*dv*dv + dv*acc.w + cb[f+3];
    *(float4*)(X + (size_t)v*HF + f) = acc;
}

// ---------------- BN stats (level 0) ----------------
__global__ __launch_bounds__(256) void k_bnstats(const float* __restrict__ X, float* __restrict__ stats){
    int c = threadIdx.x & 127, h = threadIdx.x >> 7;
    int r0 = blockIdx.x * 256;
    float s = 0.f, s2 = 0.f;
    for (int r = r0 + h; r < r0 + 256; r += 2){
        float x = X[(size_t)r*HF + c];
        s += x; s2 += x*x;
    }
    __shared__ float l1[256], l2[256];
    l1[threadIdx.x] = s; l2[threadIdx.x] = s2;
    __syncthreads();
    if (threadIdx.x < 128){
        atomicAdd(&stats[c],     l1[threadIdx.x] + l1[threadIdx.x+128]);
        atomicAdd(&stats[128+c], l2[threadIdx.x] + l2[threadIdx.x+128]);
    }
}

// ---------------- fused per-graph conv (levels 1-4): GEMM + prop + BN-stats ----------------
__global__ __launch_bounds__(1024, 4) void k_conv(
    const float* __restrict__ A, const float* __restrict__ Wg, const float* __restrict__ cb,
    const int2* __restrict__ rb2, const int2* __restrict__ cp, const float* __restrict__ dinv,
    float* __restrict__ G, float* __restrict__ X, float* __restrict__ stats,
    int n, int Nn)
{
    int g = blockIdx.x, t = threadIdx.x;
    __shared__ float Ws[64*HF];      // 32 KB
    __shared__ float red[32*HF];     // 16 KB
    int sub = t >> 8;
    int t8  = t & 255;
    int tx = t8 & 15, ty = t8 >> 4;
    int nT = (n + 255) >> 8;
    for (int tile = 0; tile < nT; ++tile){
        int r0 = tile*256 + sub*64 + ty*4;
        bool act = (r0 < n);
        float acc[4][8];
        #pragma unroll
        for (int j=0;j<4;++j)
            #pragma unroll
            for (int l=0;l<8;++l) acc[j][l] = 0.f;
        for (int kh = 0; kh < 2; ++kh){
            __syncthreads();
            {
                float4* d4 = (float4*)Ws;
                const float4* s4 = (const float4*)(Wg + kh*64*HF);
                #pragma unroll
                for (int i = 0; i < 2; ++i) d4[t + i*1024] = s4[t + i*1024];
            }
            __syncthreads();
            if (act){
                int c0 = tx*4;
                for (int k4 = 0; k4 < 16; ++k4){
                    float4 av[4];
                    #pragma unroll
                    for (int j=0;j<4;++j)
                        av[j] = *(const float4*)(A + ((size_t)g*n + r0 + j)*HF + kh*64 + k4*4);
                    #pragma unroll
                    for (int kk=0; kk<4; ++kk){
                        int kl = k4*4 + kk;
                        float4 w0 = *(const float4*)(Ws + kl*HF + c0);
                        float4 w1 = *(const float4*)(Ws + kl*HF + c0 + 64);
                        #pragma unroll
                        for (int j=0;j<4;++j){
                            float a = reinterpret_cast<const float*>(&av[j])[kk];
                            acc[j][0] += a*w0.x; acc[j][1] += a*w0.y; acc[j][2] += a*w0.z; acc[j][3] += a*w0.w;
                            acc[j][4] += a*w1.x; acc[j][5] += a*w1.y; acc[j][6] += a*w1.z; acc[j][7] += a*w1.w;
                        }
                    }
                }
            }
        }
        if (act){
            int c0 = tx*4;
            #pragma unroll
            for (int j=0;j<4;++j){
                *(float4*)(G + ((size_t)g*n + r0 + j)*HF + c0)      = make_float4(acc[j][0],acc[j][1],acc[j][2],acc[j][3]);
                *(float4*)(G + ((size_t)g*n + r0 + j)*HF + c0 + 64) = make_float4(acc[j][4],acc[j][5],acc[j][6],acc[j][7]);
            }
        }
    }
    __syncthreads();
    int f4 = t & 31;
    int f = f4*4;
    float4 s  = make_float4(0.f,0.f,0.f,0.f);
    float4 s2 = make_float4(0.f,0.f,0.f,0.f);
    float cb0 = cb[f], cb1 = cb[f+1], cb2 = cb[f+2], cb3 = cb[f+3];
    for (int l = t >> 5; l < n; l += 32){
        int v = g*n + l;
        float dv = dinv[v];
        float4 y = *(const float4*)(G + (size_t)v*HF + f);
        float4 acc = make_float4(0.f,0.f,0.f,0.f);
        int2 rb = rb2[v];
        int e0 = rb.x, e1 = rb.x + rb.y;
        for (int j = e0; j < e1; ++j){
            int2 e = cp[j];
            int sN = e.x & (Nn - 1);
            float en = __int_as_float(e.y);
            float4 h = *(const float4*)(G + (size_t)sN*HF + f);
            acc.x += en*h.x; acc.y += en*h.y; acc.z += en*h.z; acc.w += en*h.w;
        }
        acc.x = y.x*dv*dv + dv*acc.x + cb0;
        acc.y = y.y*dv*dv + dv*acc.y + cb1;
        acc.z = y.z*dv*dv + dv*acc.z + cb2;
        acc.w = y.w*dv*dv + dv*acc.w + cb3;
        *(float4*)(X + (size_t)v*HF + f) = acc;
        s.x += acc.x; s.y += acc.y; s.z += acc.z; s.w += acc.w;
        s2.x += acc.x*acc.x; s2.y += acc.y*acc.y; s2.z += acc.z*acc.z; s2.w += acc.w*acc.w;
    }
    int base = (t >> 5)*HF + f;
    __syncthreads();
    *(float4*)&red[base] = s;
    __syncthreads();
    if (t < 128){
        float a = 0.f;
        #pragma unroll
        for (int j = 0; j < 32; ++j) a += red[j*HF + t];
        atomicAdd(&stats[t], a);
    }
    __syncthreads();
    *(float4*)&red[base] = s2;
    __syncthreads();
    if (t < 128){
        float a = 0.f;
        #pragma unroll
        for (int j = 0; j < 32; ++j) a += red[j*HF + t];
        atomicAdd(&stats[128+t], a);
    }
}

// ---------------- mega-fused per-graph kernel (1024 threads) ----------------
__global__ __launch_bounds__(1024) void k_graph(
    const float* __restrict__ H, const float* __restrict__ stats,
    const float* __restrict__ gw, const float* __restrict__ gb,
    const float* __restrict__ aw, const float* __restrict__ th,
    const int2* __restrict__ rb2, int2* __restrict__ csr, const float* __restrict__ dinv,
    int* __restrict__ srcw, int* __restrict__ dstw, float* __restrict__ wv,
    float* __restrict__ P, float* __restrict__ gacc,
    int2* __restrict__ rb2n, float* __restrict__ dinvn, float* __restrict__ statsNext,
    float invN, float ca2, float cc2, float ca3, float cc3,
    int n, int last)
{
    int g = blockIdx.x, t = threadIdx.x;
    int k = n >> 1;
    __shared__ int2  eds[4096];
    __shared__ int2  rbl[512];
    __shared__ float dvv[512], p0[512], p1[512], p2[512];
    __shared__ float ss[512];
    __shared__ int   si[512];
    __shared__ float tss[256];
    __shared__ int   nid[512];
    __shared__ int   cntN[256], curN[256];
    __shared__ float dvn[256];
    __shared__ float bna[128], bnb[128];
    __shared__ float red[1024];

    if (t < 256) statsNext[t] = 0.f;
    if (t < 128){
        float mean = stats[t]*invN;
        float var  = stats[128+t]*invN - mean*mean;
        float iv   = rsqrtf(var + 1e-5f);
        bna[t] = iv*gw[t];
        bnb[t] = gb[t] - mean*iv*gw[t];
    }
    for (int l = t; l < n; l += 1024){
        int2 rb = rb2[g*n + l];
        rbl[l] = make_int2(rb.x - g*4096, rb.y);
        dvv[l] = dinv[g*n + l];
    }
    __syncthreads();
    int medg = rbl[n-1].x + rbl[n-1].y;
    for (int j = t; j < medg; j += 1024){
        int2 e = csr[g*4096 + j];
        eds[j] = make_int2(e.x & (n-1), e.y);
    }
    int lane = t & 63, wid = t >> 6;
    for (int l = wid; l < n; l += 16){
        const float* hp = H + ((size_t)g*n + l)*HF;
        float a0 = hp[lane], a1 = hp[lane+64];
        float v0 = fmaxf(a0*bna[lane]    + bnb[lane],    0.f) * aw[lane];
        float v1 = fmaxf(a1*bna[lane+64] + bnb[lane+64], 0.f) * aw[lane+64];
        float p = v0 + v1;
        for (int off = 32; off; off >>= 1) p += __shfl_down(p, off);
        if (lane == 0) p0[l] = p;
    }
    __syncthreads();
    for (int l = t; l < n; l += 1024){
        int2 rc = rbl[l];
        float acc = 0.f;
        for (int j = 0; j < rc.y; ++j){
            int2 e = eds[rc.x + j];
            acc += __int_as_float(e.y) * p0[e.x];
        }
        float dv = dvv[l];
        p1[l] = 2.f*(p0[l]*dv*dv + dv*acc);
    }
    __syncthreads();
    for (int l = t; l < n; l += 1024){
        int2 rc = rbl[l];
        float acc = 0.f;
        for (int j = 0; j < rc.y; ++j){
            int2 e = eds[rc.x + j];
            acc += __int_as_float(e.y) * p1[e.x];
        }
        float dv = dvv[l];
        p2[l] = ca2*(p1[l]*dv*dv + dv*acc) + cc2*p0[l];
    }
    __syncthreads();
    float t0v = th[0], t1v = th[1], t2c = th[2], t3v = th[3];
    for (int l = t; l < n; l += 1024){
        int2 rc = rbl[l];
        float acc = 0.f;
        for (int j = 0; j < rc.y; ++j){
            int2 e = eds[rc.x + j];
            acc += __int_as_float(e.y) * p2[e.x];
        }
        float dv = dvv[l];
        float tv = p2[l]*dv*dv + dv*acc;
        float p3 = ca3*tv + cc3*p1[l];
        ss[l] = t0v*p0[l] + t1v*p1[l] + t2c*p2[l] + t3v*p3;
        si[l] = l;
    }
    __syncthreads();
    for (int size = 2; size <= n; size <<= 1){
        for (int stride = size >> 1; stride > 0; stride >>= 1){
            for (int i = t; i < n; i += 1024){
                int j = i ^ stride;
                if (j > i){
                    bool asc = ((i & size) == 0);
                    float s1 = ss[i], s2 = ss[j];
                    int   i1 = si[i], i2 = si[j];
                    bool gt = (s1 < s2) || (s1 == s2 && i1 > i2);
                    if (gt == asc){ ss[i] = s2; ss[j] = s1; si[i] = i2; si[j] = i1; }
                }
            }
            __syncthreads();
        }
    }
    for (int l = t; l < n; l += 1024) nid[l] = -1;
    __syncthreads();
    for (int r = t; r < k; r += 1024){
        nid[si[r]] = r;
        tss[r] = tanhf(ss[r]);
    }
    __syncthreads();
    {
        int f = t & 127, rl = t >> 7;
        float af = bna[f], bf = bnb[f];
        float mx = -3.4e38f, sm = 0.f;
        for (int r = rl; r < k; r += 8){
            int old = si[r];
            float hv = H[((size_t)g*n + old)*HF + f];
            float v = fmaxf(hv*af + bf, 0.f) * tss[r];
            P[((size_t)g*k + r)*HF + f] = v;
            mx = fmaxf(mx, v); sm += v;
        }
        red[t] = mx;
        __syncthreads();
        if (t < 512) red[t] = fmaxf(red[t], red[t+512]);
        __syncthreads();
        if (t < 256) red[t] = fmaxf(red[t], red[t+256]);
        __syncthreads();
        if (t < 128) gacc[g*256 + t] += fmaxf(red[t], red[t+128]);
        __syncthreads();
        red[t] = sm;
        __syncthreads();
        if (t < 512) red[t] += red[t+512];
        __syncthreads();
        if (t < 256) red[t] += red[t+256];
        __syncthreads();
        if (t < 128) gacc[g*256 + 128 + t] += (red[t] + red[t+128]) / (float)k;
    }
    if (last) return;
    __syncthreads();
    if (t < k) cntN[t] = 0;
    __syncthreads();
    for (int j = t; j < 4096; j += 1024){
        int e = g*4096 + j;
        float we = wv[e];
        int valid = 0, ns = 0, nd = 0;
        if (we > 0.5f){
            int sl = srcw[e] & (n-1);
            int dl = dstw[e] & (n-1);
            ns = nid[sl]; nd = nid[dl];
            valid = (ns >= 0) && (nd >= 0);
        }
        if (valid){
            srcw[e] = g*k + ns; dstw[e] = g*k + nd; wv[e] = 1.f;
            atomicAdd(&cntN[nd], 1);
        } else {
            srcw[e] = 0; dstw[e] = 0; wv[e] = 0.f;
        }
    }
    __syncthreads();
    int c = (t < 256) ? ((t < k) ? cntN[t] : 0) : 0;
    if (t < 256) si[t] = c;
    __syncthreads();
    for (int off = 1; off < 256; off <<= 1){
        int a = 0;
        if (t < 256 && t >= off) a = si[t-off];
        __syncthreads();
        if (t < 256) si[t] += a;
        __syncthreads();
    }
    if (t < k){
        int beg = si[t] - c;
        rb2n[g*k + t] = make_int2(g*4096 + beg, c);
        float dv = rsqrtf((float)c + 1.f);
        dinvn[g*k + t] = dv;
        dvn[t] = dv;
        curN[t] = beg;
    }
    __syncthreads();
    for (int j = t; j < 4096; j += 1024){
        int e = g*4096 + j;
        if (wv[e] > 0.5f){
            int sg = srcw[e], dl = dstw[e] & (k-1);
            int p = atomicAdd(&curN[dl], 1);
            csr[g*4096 + p] = make_int2(sg, __float_as_int(dvn[sg & (k-1)]));
        }
    }
}

// ---------------- head ----------------
__global__ __launch_bounds__(256) void k_head1(const float* __restrict__ gacc, const float* __restrict__ W1,
                                               const float* __restrict__ b1, float* __restrict__ t1,
                                               float* __restrict__ sh){
    int r = blockIdx.x;
    int c = threadIdx.x & 127, h = threadIdx.x >> 7;
    __shared__ float gs[256];
    __shared__ float red[256];
    gs[threadIdx.x] = gacc[r*256 + threadIdx.x];
    __syncthreads();
    float s = 0.f;
    #pragma unroll
    for (int kk = 0; kk < 128; ++kk)
        s += gs[h*128 + kk] * W1[(h*128 + kk)*128 + c];
    red[threadIdx.x] = s;
    __syncthreads();
    if (h == 0){
        float v = (red[c] + red[c+128]) * 0.2f + b1[c];
        t1[r*128 + c] = v;
        atomicAdd(&sh[c], v);
        atomicAdd(&sh[128 + c], v*v);
    }
}
__global__ __launch_bounds__(128) void k_head2(const float* __restrict__ t1, const float* __restrict__ gw,
                                               const float* __restrict__ gb, const float* __restrict__ W2,
                                               const float* __restrict__ b2, float* __restrict__ sh,
                                               float* __restrict__ t2){
    int r = blockIdx.x, t = threadIdx.x;
    int cc = t & 63, h = t >> 6;
    __shared__ float row[128];
    __shared__ float red[128];
    {
        float mean = sh[t] * (1.f/128.f);
        float var  = sh[128+t]*(1.f/128.f) - mean*mean;
        float iv   = rsqrtf(var + 1e-5f);
        float v = (t1[r*128+t] - mean)*iv*gw[t] + gb[t];
        row[t] = fmaxf(v, 0.f);
    }
    __syncthreads();
    float s = 0.f;
    #pragma unroll
    for (int kk = 0; kk < 64; ++kk)
        s += row[h*64+kk] * W2[(h*64+kk)*64 + cc];
    red[t] = s;
    __syncthreads();
    if (h == 0){
        float v = red[cc] + red[cc+64] + b2[cc];
        t2[r*64+cc] = v;
        atomicAdd(&sh[256+cc], v);
        atomicAdd(&sh[320+cc], v*v);
    }
}
__global__ __launch_bounds__(64) void k_head3(const float* __restrict__ t2, const float* __restrict__ gw,
                                              const float* __restrict__ gb, const float* __restrict__ W3,
                                              const float* __restrict__ b3, const float* __restrict__ sh,
                                              float* __restrict__ out){
    int r = blockIdx.x, t = threadIdx.x;
    float mean = sh[256+t]*(1.f/128.f);
    float var  = sh[320+t]*(1.f/128.f) - mean*mean;
    float iv   = rsqrtf(var + 1e-5f);
    float v = fmaxf((t2[r*64+t]-mean)*iv*gw[t] + gb[t], 0.f);
    float lg[10];
    #pragma unroll
    for (int j = 0; j < 10; ++j){
        float p = v * W3[t*10 + j];
        for (int off = 32; off; off >>= 1) p += __shfl_down(p, off);
        lg[j] = p;
    }
    if (t == 0){
        float m = -3.4e38f;
        #pragma unroll
        for (int j = 0; j < 10; ++j){ lg[j] += b3[j]; m = fmaxf(m, lg[j]); }
        float se = 0.f;
        #pragma unroll
        for (int j = 0; j < 10; ++j) se += expf(lg[j] - m);
        float l = logf(se) + m;
        #pragma unroll
        for (int j = 0; j < 10; ++j) out[r*10 + j] = lg[j] - l;
    }
}

extern "C" void kernel_launch(void* const* d_in, const int* in_sizes, int n_in,
                              void* d_out, int out_size, void* d_ws, size_t ws_size,
                              hipStream_t stream){
    const float* x     = (const float*)d_in[0];
    const float* convW = (const float*)d_in[1];
    const float* convb = (const float*)d_in[2];
    const float* bnW   = (const float*)d_in[3];
    const float* bnB   = (const float*)d_in[4];
    const float* bn7W  = (const float*)d_in[5];
    const float* bn7B  = (const float*)d_in[6];
    const float* attW  = (const float*)d_in[7];
    const float* theta = (const float*)d_in[8];
    const float* lin1W = (const float*)d_in[9];
    const float* lin1b = (const float*)d_in[10];
    const float* lin2W = (const float*)d_in[11];
    const float* lin2b = (const float*)d_in[12];
    const float* lin3W = (const float*)d_in[13];
    const float* lin3b = (const float*)d_in[14];
    const int*   src0  = (const int*)d_in[15];
    const int*   dst0  = (const int*)d_in[16];

    char* base = (char*)d_ws;
    size_t off = 0;
    auto take = [&](size_t bytes) -> void* {
        void* p = base + off;
        off = (off + bytes + 255) & ~(size_t)255;
        return p;
    };
    float* bufGP = (float*)take((size_t)N0G*HF*4);
    float* bufH  = (float*)take((size_t)N0G*HF*4);
    int*   srcw  = (int*)  take((size_t)ETOT*4);
    int*   dstw  = (int*)  take((size_t)ETOT*4);
    float* w     = (float*)take((size_t)ETOT*4);
    int2*  csr_p = (int2*) take((size_t)ETOT*8);
    int2*  rb2A  = (int2*) take((size_t)N0G*8);
    int2*  rb2B  = (int2*) take((size_t)N0G*8);
    float* dinvA = (float*)take((size_t)N0G*4);
    float* dinvB = (float*)take((size_t)N0G*4);
    float* stats0= (float*)take(256*4);
    float* stats1= (float*)take(256*4);
    float* gacc  = (float*)take((size_t)B_GRAPH*256*4);
    float* t1    = (float*)take((size_t)B_GRAPH*128*4);
    float* t2    = (float*)take((size_t)B_GRAPH*64*4);
    float* statsH= (float*)take(384*4);

    auto coef = [](int kk, float& ca, float& cc){
        double a = 1.0, b = 1.0;
        double c0 = 2.0*kk*(kk+a+b)*(2.0*kk+a+b-2.0);
        double c1 = (2.0*kk+a+b-1.0)*(2.0*kk+a+b)*(2.0*kk+a+b-2.0);
        double c3 = 2.0*(kk+a-1.0)*(kk+b-1.0)*(2.0*kk+a+b);
        ca = (float)(c1/c0); cc = (float)(-c3/c0);
    };
    float ca2, cc2, ca3, cc3;
    coef(2, ca2, cc2);
    coef(3, ca3, cc3);

    k_init<<<B_GRAPH, 256, 0, stream>>>(src0, dst0, srcw, dstw, w, csr_p, rb2A, dinvA,
                                        gacc, statsH, stats0, stats1);

    for (int i = 0; i < 5; ++i){
        int n = 512 >> i;
        int Nn = B_GRAPH*n;
        int2*  rb_cur = (i & 1) ? rb2B : rb2A;
        int2*  rb_nxt = (i & 1) ? rb2A : rb2B;
        float* dv_cur = (i & 1) ? dinvB : dinvA;
        float* dv_nxt = (i & 1) ? dinvA : dinvB;
        float* st_cur = (i & 1) ? stats1 : stats0;
        float* st_nxt = (i & 1) ? stats0 : stats1;
        const float* convA = (i == 0) ? x : bufGP;
        float* G = (i == 0) ? bufGP : (bufGP + (size_t)4*1024*1024);

        if (i == 0){
            // chip-wide path for the big level
            k_gemm<<<Nn/64, 256, 0, stream>>>(convA, convW, G);
            k_prop<<<Nn/8, 256, 0, stream>>>(G, convb, rb_cur, csr_p, dv_cur, bufH, n, 6, Nn);
            k_bnstats<<<Nn/256, 256, 0, stream>>>(bufH, st_cur);
        } else {
            k_conv<<<B_GRAPH, 1024, 0, stream>>>(convA, convW + (size_t)i*HF*HF, convb + i*HF,
                                                 rb_cur, csr_p, dv_cur, G, bufH, st_cur, n, Nn);
        }
        k_graph<<<B_GRAPH, 1024, 0, stream>>>(bufH, st_cur, bnW + i*HF, bnB + i*HF, attW + i*HF,
                                              theta + i*4, rb_cur, csr_p, dv_cur,
                                              srcw, dstw, w, bufGP, gacc, rb_nxt, dv_nxt, st_nxt,
                                              1.0f/(float)Nn, ca2, cc2, ca3, cc3, n, (i == 4) ? 1 : 0);
    }

    k_head1<<<B_GRAPH, 256, 0, stream>>>(gacc, lin1W, lin1b, t1, statsH);
    k_head2<<<B_GRAPH, 128, 0, stream>>>(t1, bnW + 5*HF, bnB + 5*HF, lin2W, lin2b, statsH, t2);
    k_head3<<<B_GRAPH, 64, 0, stream>>>(t2, bn7W, bn7B, lin3W, lin3b, statsH, (float*)d_out);
}